// Round 1
// baseline (842.697 us; speedup 1.0000x reference)
//
#include <hip/hip_runtime.h>
#include <hip/hip_bf16.h>
#include <math.h>

namespace {

constexpr int kN0 = 100000, kN1 = 25000, kN2 = 6250;
constexpr int kE0 = 1600000, kE1 = 400000, kE2 = 100000;
// Concatenated-edge layout: [A0 | A1 | A2 | T0(assign0) | T1(assign1)]
constexpr int kEO1 = kE0;                   // 1,600,000
constexpr int kEO2 = kEO1 + kE1;            // 2,000,000
constexpr int kEO3 = kEO2 + kE2;            // 2,100,000
constexpr int kEO4 = kEO3 + kN0;            // 2,200,000
constexpr int kTE  = kEO4 + kN1;            // 2,225,000
// Concatenated-bin layout (destination node counts per graph)
constexpr int kBO1 = kN0;                   // A1 bins
constexpr int kBO2 = kBO1 + kN1;            // A2 bins
constexpr int kBO3 = kBO2 + kN2;            // T0 bins
constexpr int kBO4 = kBO3 + kN1;            // T1 bins
constexpr int kTB  = kBO4 + kN2;            // 162,500
// 8 XCD-replicated histogram: counts8[bin*8 + xcd]
constexpr int kTB8 = kTB * 8;               // 1,300,000
constexpr int kScanPer = 8192;              // elems per scan1 block (32/thread)
constexpr int kNBLK = (kTB8 + kScanPer - 1) / kScanPer;  // 159 scan blocks

__device__ __forceinline__ float bf_lo(unsigned int u) {
  return __uint_as_float(u << 16);
}
__device__ __forceinline__ float bf_hi(unsigned int u) {
  return __uint_as_float(u & 0xffff0000u);
}
__device__ __forceinline__ unsigned short f2bf(float f) {
  __hip_bfloat16 h = __float2bfloat16(f);
  return *reinterpret_cast<unsigned short*>(&h);
}

// Real chiplet id (0..7). HW_REG_XCC_ID = id 20; getreg imm = (size-1)<<11 |
// offset<<6 | id. Reading the HW id (not guessing from blockIdx) is what makes
// the XCD-local-atomic scheme correct regardless of dispatch mapping.
__device__ __forceinline__ int xcd_id() {
  return __builtin_amdgcn_s_getreg((31 << 11) | (0 << 6) | 20) & 7;
}

// edge id -> (dst, boff) for count; full decode for place
__device__ __forceinline__ void edge_bin(
    int t, const int* a0i, const int* a1i, const int* a2i,
    const int* as0, const int* as1, int& dst, int& boff) {
  if (t < kEO1)      { dst = a0i[t];        boff = 0;    }
  else if (t < kEO2) { dst = a1i[t - kEO1]; boff = kBO1; }
  else if (t < kEO3) { dst = a2i[t - kEO2]; boff = kBO2; }
  else if (t < kEO4) { dst = as0[t - kEO3]; boff = kBO3; }
  else               { dst = as1[t - kEO4]; boff = kBO4; }
}

__device__ __forceinline__ void edge_decode(
    int t, const int* a0i, const float* a0v, const int* a1i, const int* a2i,
    const int* as0, const int* as1, int& dst, int& src, int& boff, float& val) {
  if (t < kEO1)      { dst = a0i[t]; src = a0i[kE0 + t]; val = a0v[t]; boff = 0; }
  else if (t < kEO2) { int e = t - kEO1; dst = a1i[e]; src = a1i[kE1 + e]; val = 1.0f; boff = kBO1; }
  else if (t < kEO3) { int e = t - kEO2; dst = a2i[e]; src = a2i[kE2 + e]; val = 1.0f; boff = kBO2; }
  else if (t < kEO4) { int e = t - kEO3; dst = as0[e]; src = e;            val = 1.0f; boff = kBO3; }
  else               { int e = t - kEO4; dst = as1[e]; src = e;            val = 1.0f; boff = kBO4; }
}

// ---------------------------------------------------------------------------
// CSR build, XCD-local-atomic version:
//   count (workgroup-scope atomics into per-XCD histogram replicas)
//   -> in-place scan over [bin][xcd] (gives slot starts AND row_ptr)
//   -> place (returning workgroup-scope atomic = final slot, no rank array)
// Device-scope atomics write through to the coherence point (~32B each, the
// old rank_kernel's 78MB WRITE_SIZE); XCD-local replicas keep the RMW in the
// local L2.
// ---------------------------------------------------------------------------
constexpr int kRankT = (kTE + 3) / 4;  // threads; edge ids t, t+T, t+2T, t+3T

__global__ __launch_bounds__(256) void count_kernel(
    const int* __restrict__ a0i, const int* __restrict__ a1i,
    const int* __restrict__ a2i, const int* __restrict__ as0,
    const int* __restrict__ as1, int* __restrict__ counts8) {
  int tid = blockIdx.x * 256 + threadIdx.x;
  if (tid >= kRankT) return;
  int xcd = xcd_id();
  #pragma unroll
  for (int i = 0; i < 4; ++i) {
    int t = tid + i * kRankT;
    if (t < kTE) {
      int dst, boff;
      edge_bin(t, a0i, a1i, a2i, as0, as1, dst, boff);
      // Non-returning, XCD-local atomic: executes in this XCD's L2.
      __hip_atomic_fetch_add(&counts8[(boff + dst) * 8 + xcd], 1,
                             __ATOMIC_RELAXED, __HIP_MEMORY_SCOPE_WORKGROUP);
    }
  }
}

// In-place exclusive scan, 32 elems/thread (8192/block). Safe in-place: each
// thread reads its own 32 elements into registers before any write.
__global__ __launch_bounds__(256) void scan1_kernel(
    int* __restrict__ data, int* __restrict__ partials, int n) {
  __shared__ int sdata[256];
  int t = threadIdx.x;
  int base = blockIdx.x * kScanPer + t * 32;
  int4 v[8];
  int s = 0;
  #pragma unroll
  for (int j = 0; j < 8; ++j) {
    int idx = base + j * 4;
    if (idx < n) v[j] = *(const int4*)&data[idx];
    else v[j] = make_int4(0, 0, 0, 0);
    s += v[j].x + v[j].y + v[j].z + v[j].w;
  }
  sdata[t] = s;
  __syncthreads();
  for (int off = 1; off < 256; off <<= 1) {
    int x = (t >= off) ? sdata[t - off] : 0;
    __syncthreads();
    sdata[t] += x;
    __syncthreads();
  }
  int run = sdata[t] - s;
  #pragma unroll
  for (int j = 0; j < 8; ++j) {
    int idx = base + j * 4;
    int4 o;
    o.x = run; run += v[j].x;
    o.y = run; run += v[j].y;
    o.z = run; run += v[j].z;
    o.w = run; run += v[j].w;
    if (idx < n) *(int4*)&data[idx] = o;
  }
  if (t == 255) partials[blockIdx.x] = sdata[255];
}

__global__ __launch_bounds__(256) void scan2_kernel(int* partials, int nb) {
  __shared__ int sdata[256];
  int t = threadIdx.x;
  sdata[t] = (t < nb) ? partials[t] : 0;
  __syncthreads();
  for (int off = 1; off < 256; off <<= 1) {
    int x = (t >= off) ? sdata[t - off] : 0;
    __syncthreads();
    sdata[t] += x;
    __syncthreads();
  }
  if (t < nb) partials[t] = (t == 0) ? 0 : sdata[t - 1];
}

// Add block offsets; extract compact row_ptr[bin] = pos of (bin, xcd=0).
__global__ __launch_bounds__(256) void scan3_kernel(
    int* __restrict__ pos8, const int* __restrict__ partials,
    int* __restrict__ row_ptr, int n) {
  int i = blockIdx.x * 256 + threadIdx.x;
  if (i < n) {
    int v = pos8[i] + partials[i >> 13];  // 8192 = 2^13
    pos8[i] = v;
    if ((i & 7) == 0) row_ptr[i >> 3] = v;
  }
  if (i == 0) row_ptr[kTB] = kTE;
}

__global__ __launch_bounds__(256) void place_kernel(
    const int* __restrict__ a0i, const float* __restrict__ a0v,
    const int* __restrict__ a1i, const int* __restrict__ a2i,
    const int* __restrict__ as0, const int* __restrict__ as1,
    int* __restrict__ pos8, int2* __restrict__ edges) {
  int tid = blockIdx.x * 256 + threadIdx.x;
  if (tid >= kRankT) return;
  int xcd = xcd_id();
  int pos[4]; int2 rec[4];
  #pragma unroll
  for (int i = 0; i < 4; ++i) {
    int t = tid + i * kRankT;
    if (t < kTE) {
      int dst, src, boff; float val;
      edge_decode(t, a0i, a0v, a1i, a2i, as0, as1, dst, src, boff, val);
      // Returning XCD-local atomic = final slot in the CSR (rows stay
      // contiguous because the scan is over the flattened [bin][xcd] order).
      pos[i] = __hip_atomic_fetch_add(&pos8[(boff + dst) * 8 + xcd], 1,
                                      __ATOMIC_RELAXED,
                                      __HIP_MEMORY_SCOPE_WORKGROUP);
      rec[i] = make_int2(src, __float_as_int(val));
    }
  }
  #pragma unroll
  for (int i = 0; i < 4; ++i) {
    int t = tid + i * kRankT;
    if (t < kTE) edges[pos[i]] = rec[i];
  }
}

// ---------------------------------------------------------------------------
// GEMM C[M,128] = A[M,128] @ W[128,128]; fp32 and/or bf16 outputs.
// ---------------------------------------------------------------------------
__global__ __launch_bounds__(256) void gemm128_kernel(
    const float* __restrict__ A, const float* __restrict__ W,
    float* __restrict__ Cf, unsigned short* __restrict__ Cb, int M) {
  __shared__ float As[64 * 132];
  int t = threadIdx.x;
  int row0 = blockIdx.x << 6;
  #pragma unroll
  for (int i = 0; i < 8; ++i) {
    int f = t + (i << 8);
    int r = f >> 5, c4 = (f & 31) << 2;
    int gr = row0 + r;
    float4 v = make_float4(0.f, 0.f, 0.f, 0.f);
    if (gr < M) v = *(const float4*)&A[(size_t)gr * 128 + c4];
    *(float4*)&As[r * 132 + c4] = v;
  }
  __syncthreads();
  int wcol = t & 31;
  int c4 = wcol << 2;
  int rsub = t >> 5;
  float4 acc[8];
  #pragma unroll
  for (int j = 0; j < 8; ++j) acc[j] = make_float4(0.f, 0.f, 0.f, 0.f);
  const float4* W4 = (const float4*)W;
  #pragma unroll 4
  for (int k = 0; k < 128; ++k) {
    float4 w = W4[k * 32 + wcol];
    #pragma unroll
    for (int j = 0; j < 8; ++j) {
      float a = As[(rsub + (j << 3)) * 132 + k];
      acc[j].x = fmaf(a, w.x, acc[j].x);
      acc[j].y = fmaf(a, w.y, acc[j].y);
      acc[j].z = fmaf(a, w.z, acc[j].z);
      acc[j].w = fmaf(a, w.w, acc[j].w);
    }
  }
  #pragma unroll
  for (int j = 0; j < 8; ++j) {
    int gr = row0 + rsub + (j << 3);
    if (gr < M) {
      if (Cf) *(float4*)&Cf[(size_t)gr * 128 + c4] = acc[j];
      if (Cb) {
        ushort4 b;
        b.x = f2bf(acc[j].x); b.y = f2bf(acc[j].y);
        b.z = f2bf(acc[j].z); b.w = f2bf(acc[j].w);
        *(ushort4*)&Cb[(size_t)gr * 128 + c4] = b;
      }
    }
  }
}

// Fused Q/K projection: one LDS tile of A, two K-loops (Wq -> fp32, Wk -> bf16).
__global__ __launch_bounds__(256) void gemm128_qk_kernel(
    const float* __restrict__ A, const float* __restrict__ Wq,
    const float* __restrict__ Wk, float* __restrict__ Qf,
    unsigned short* __restrict__ Kb, int M) {
  __shared__ float As[64 * 132];
  int t = threadIdx.x;
  int row0 = blockIdx.x << 6;
  #pragma unroll
  for (int i = 0; i < 8; ++i) {
    int f = t + (i << 8);
    int r = f >> 5, c4 = (f & 31) << 2;
    int gr = row0 + r;
    float4 v = make_float4(0.f, 0.f, 0.f, 0.f);
    if (gr < M) v = *(const float4*)&A[(size_t)gr * 128 + c4];
    *(float4*)&As[r * 132 + c4] = v;
  }
  __syncthreads();
  int wcol = t & 31;
  int c4 = wcol << 2;
  int rsub = t >> 5;
  float4 acc[8];
  const float4* Wq4 = (const float4*)Wq;
  const float4* Wk4 = (const float4*)Wk;
  #pragma unroll
  for (int j = 0; j < 8; ++j) acc[j] = make_float4(0.f, 0.f, 0.f, 0.f);
  #pragma unroll 4
  for (int k = 0; k < 128; ++k) {
    float4 w = Wq4[k * 32 + wcol];
    #pragma unroll
    for (int j = 0; j < 8; ++j) {
      float a = As[(rsub + (j << 3)) * 132 + k];
      acc[j].x = fmaf(a, w.x, acc[j].x);
      acc[j].y = fmaf(a, w.y, acc[j].y);
      acc[j].z = fmaf(a, w.z, acc[j].z);
      acc[j].w = fmaf(a, w.w, acc[j].w);
    }
  }
  #pragma unroll
  for (int j = 0; j < 8; ++j) {
    int gr = row0 + rsub + (j << 3);
    if (gr < M) *(float4*)&Qf[(size_t)gr * 128 + c4] = acc[j];
  }
  #pragma unroll
  for (int j = 0; j < 8; ++j) acc[j] = make_float4(0.f, 0.f, 0.f, 0.f);
  #pragma unroll 4
  for (int k = 0; k < 128; ++k) {
    float4 w = Wk4[k * 32 + wcol];
    #pragma unroll
    for (int j = 0; j < 8; ++j) {
      float a = As[(rsub + (j << 3)) * 132 + k];
      acc[j].x = fmaf(a, w.x, acc[j].x);
      acc[j].y = fmaf(a, w.y, acc[j].y);
      acc[j].z = fmaf(a, w.z, acc[j].z);
      acc[j].w = fmaf(a, w.w, acc[j].w);
    }
  }
  #pragma unroll
  for (int j = 0; j < 8; ++j) {
    int gr = row0 + rsub + (j << 3);
    if (gr < M) {
      ushort4 b;
      b.x = f2bf(acc[j].x); b.y = f2bf(acc[j].y);
      b.z = f2bf(acc[j].z); b.w = f2bf(acc[j].w);
      *(ushort4*)&Kb[(size_t)gr * 128 + c4] = b;
    }
  }
}

// C[M,40] = A[M,128] @ W[128,40], bf16 output (consumed by gathers only)
__global__ __launch_bounds__(256) void gemm40_kernel(
    const float* __restrict__ A, const float* __restrict__ W,
    unsigned short* __restrict__ Cb, int M) {
  __shared__ float Ws[128 * 40];
  __shared__ float As[64 * 132];
  int t = threadIdx.x;
  int row0 = blockIdx.x << 6;
  #pragma unroll
  for (int i = 0; i < 5; ++i)
    ((float4*)Ws)[t + i * 256] = ((const float4*)W)[t + i * 256];
  #pragma unroll
  for (int i = 0; i < 8; ++i) {
    int f = t + (i << 8);
    int r = f >> 5, c4 = (f & 31) << 2;
    int gr = row0 + r;
    float4 v = make_float4(0.f, 0.f, 0.f, 0.f);
    if (gr < M) v = *(const float4*)&A[(size_t)gr * 128 + c4];
    *(float4*)&As[r * 132 + c4] = v;
  }
  __syncthreads();
  int r = t >> 2;
  int cg = (t & 3) * 10;
  float acc[10];
  #pragma unroll
  for (int j = 0; j < 10; ++j) acc[j] = 0.f;
  for (int k = 0; k < 128; ++k) {
    float a = As[r * 132 + k];
    #pragma unroll
    for (int j = 0; j < 10; ++j) acc[j] = fmaf(a, Ws[k * 40 + cg + j], acc[j]);
  }
  int gr = row0 + r;
  if (gr < M) {
    #pragma unroll
    for (int j = 0; j < 10; ++j) Cb[(size_t)gr * 40 + cg + j] = f2bf(acc[j]);
  }
}

// ---------------------------------------------------------------------------
// Pull-SpMM over CSR: one wave per dst row, 128 cols (2/lane), 4-way MLP.
// ---------------------------------------------------------------------------
template <bool BF16>
__global__ __launch_bounds__(256) void spmm128_kernel(
    const int* __restrict__ row_ptr, const int2* __restrict__ edges,
    const void* __restrict__ Xv, float* __restrict__ Y,
    const float* __restrict__ bias, int nrows, int do_relu) {
  int wid = (blockIdx.x * 256 + threadIdx.x) >> 6;
  int lane = threadIdx.x & 63;
  if (wid >= nrows) return;
  int start = row_ptr[wid], end = row_ptr[wid + 1];
  const unsigned short* Xb = (const unsigned short*)Xv;
  const float* Xf = (const float*)Xv;
  float2 accA = make_float2(0.f, 0.f), accB = make_float2(0.f, 0.f);
  for (int base = start; base < end; base += 64) {
    int cnt = end - base; if (cnt > 64) cnt = 64;
    int2 e_l = make_int2(0, 0);
    if (lane < cnt) e_l = edges[base + lane];
    int j = 0;
    for (; j + 4 <= cnt; j += 4) {
      int s0 = __shfl(e_l.x, j + 0), s1 = __shfl(e_l.x, j + 1);
      int s2 = __shfl(e_l.x, j + 2), s3 = __shfl(e_l.x, j + 3);
      float v0 = __int_as_float(__shfl(e_l.y, j + 0));
      float v1 = __int_as_float(__shfl(e_l.y, j + 1));
      float v2 = __int_as_float(__shfl(e_l.y, j + 2));
      float v3 = __int_as_float(__shfl(e_l.y, j + 3));
      if (BF16) {
        unsigned int u0 = *(const unsigned int*)(Xb + (size_t)s0 * 128 + lane * 2);
        unsigned int u1 = *(const unsigned int*)(Xb + (size_t)s1 * 128 + lane * 2);
        unsigned int u2 = *(const unsigned int*)(Xb + (size_t)s2 * 128 + lane * 2);
        unsigned int u3 = *(const unsigned int*)(Xb + (size_t)s3 * 128 + lane * 2);
        accA.x = fmaf(v0, bf_lo(u0), accA.x); accA.y = fmaf(v0, bf_hi(u0), accA.y);
        accB.x = fmaf(v1, bf_lo(u1), accB.x); accB.y = fmaf(v1, bf_hi(u1), accB.y);
        accA.x = fmaf(v2, bf_lo(u2), accA.x); accA.y = fmaf(v2, bf_hi(u2), accA.y);
        accB.x = fmaf(v3, bf_lo(u3), accB.x); accB.y = fmaf(v3, bf_hi(u3), accB.y);
      } else {
        float2 x0 = *(const float2*)(Xf + (size_t)s0 * 128 + lane * 2);
        float2 x1 = *(const float2*)(Xf + (size_t)s1 * 128 + lane * 2);
        float2 x2 = *(const float2*)(Xf + (size_t)s2 * 128 + lane * 2);
        float2 x3 = *(const float2*)(Xf + (size_t)s3 * 128 + lane * 2);
        accA.x = fmaf(v0, x0.x, accA.x); accA.y = fmaf(v0, x0.y, accA.y);
        accB.x = fmaf(v1, x1.x, accB.x); accB.y = fmaf(v1, x1.y, accB.y);
        accA.x = fmaf(v2, x2.x, accA.x); accA.y = fmaf(v2, x2.y, accA.y);
        accB.x = fmaf(v3, x3.x, accB.x); accB.y = fmaf(v3, x3.y, accB.y);
      }
    }
    for (; j < cnt; ++j) {
      int src = __shfl(e_l.x, j);
      float val = __int_as_float(__shfl(e_l.y, j));
      if (BF16) {
        unsigned int u = *(const unsigned int*)(Xb + (size_t)src * 128 + lane * 2);
        accA.x = fmaf(val, bf_lo(u), accA.x);
        accA.y = fmaf(val, bf_hi(u), accA.y);
      } else {
        float2 xv = *(const float2*)(Xf + (size_t)src * 128 + lane * 2);
        accA.x = fmaf(val, xv.x, accA.x);
        accA.y = fmaf(val, xv.y, accA.y);
      }
    }
  }
  float2 acc = make_float2(accA.x + accB.x, accA.y + accB.y);
  if (bias) { acc.x += bias[lane * 2]; acc.y += bias[lane * 2 + 1]; }
  if (do_relu) { acc.x = fmaxf(acc.x, 0.f); acc.y = fmaxf(acc.y, 0.f); }
  *(float2*)&Y[(size_t)wid * 128 + lane * 2] = acc;
}

// Pool (T-graph pull sum) fused with nwgt-embedding add, 4-way MLP.
__global__ __launch_bounds__(256) void pool_emb_kernel(
    const int* __restrict__ row_ptr, const int2* __restrict__ edges,
    const float* __restrict__ X, const int* __restrict__ nwgt,
    const float* __restrict__ emb, float* __restrict__ Hpool,
    float* __restrict__ H0, unsigned short* __restrict__ H0b, int nrows) {
  int wid = (blockIdx.x * 256 + threadIdx.x) >> 6;
  int lane = threadIdx.x & 63;
  if (wid >= nrows) return;
  int start = row_ptr[wid], end = row_ptr[wid + 1];
  float2 accA = make_float2(0.f, 0.f), accB = make_float2(0.f, 0.f);
  for (int base = start; base < end; base += 64) {
    int cnt = end - base; if (cnt > 64) cnt = 64;
    int s_l = 0;
    if (lane < cnt) s_l = edges[base + lane].x;
    int j = 0;
    for (; j + 4 <= cnt; j += 4) {
      int s0 = __shfl(s_l, j + 0), s1 = __shfl(s_l, j + 1);
      int s2 = __shfl(s_l, j + 2), s3 = __shfl(s_l, j + 3);
      float2 x0 = *(const float2*)&X[(size_t)s0 * 128 + lane * 2];
      float2 x1 = *(const float2*)&X[(size_t)s1 * 128 + lane * 2];
      float2 x2 = *(const float2*)&X[(size_t)s2 * 128 + lane * 2];
      float2 x3 = *(const float2*)&X[(size_t)s3 * 128 + lane * 2];
      accA.x += x0.x + x2.x; accA.y += x0.y + x2.y;
      accB.x += x1.x + x3.x; accB.y += x1.y + x3.y;
    }
    for (; j < cnt; ++j) {
      int src = __shfl(s_l, j);
      float2 xv = *(const float2*)&X[(size_t)src * 128 + lane * 2];
      accA.x += xv.x; accA.y += xv.y;
    }
  }
  float2 acc = make_float2(accA.x + accB.x, accA.y + accB.y);
  *(float2*)&Hpool[(size_t)wid * 128 + lane * 2] = acc;
  float2 ev = *(const float2*)&emb[(size_t)nwgt[wid] * 128 + lane * 2];
  float2 h0 = make_float2(acc.x + ev.x, acc.y + ev.y);
  *(float2*)&H0[(size_t)wid * 128 + lane * 2] = h0;
  unsigned int packed = ((unsigned int)f2bf(h0.x)) | (((unsigned int)f2bf(h0.y)) << 16);
  *(unsigned int*)(H0b + (size_t)wid * 128 + lane * 2) = packed;
}

__global__ __launch_bounds__(256) void spmm40_kernel(
    const int* __restrict__ row_ptr, const int2* __restrict__ edges,
    const unsigned short* __restrict__ Xb, float* __restrict__ Y,
    const float* __restrict__ bias, int nrows) {
  int wid = (blockIdx.x * 256 + threadIdx.x) >> 6;
  int lane = threadIdx.x & 63;
  if (wid >= nrows) return;
  int start = row_ptr[wid], end = row_ptr[wid + 1];
  float accA = 0.f, accB = 0.f;
  for (int base = start; base < end; base += 64) {
    int cnt = end - base; if (cnt > 64) cnt = 64;
    int2 e_l = make_int2(0, 0);
    if (lane < cnt) e_l = edges[base + lane];
    int j = 0;
    for (; j + 4 <= cnt; j += 4) {
      int s0 = __shfl(e_l.x, j + 0), s1 = __shfl(e_l.x, j + 1);
      int s2 = __shfl(e_l.x, j + 2), s3 = __shfl(e_l.x, j + 3);
      float v0 = __int_as_float(__shfl(e_l.y, j + 0));
      float v1 = __int_as_float(__shfl(e_l.y, j + 1));
      float v2 = __int_as_float(__shfl(e_l.y, j + 2));
      float v3 = __int_as_float(__shfl(e_l.y, j + 3));
      if (lane < 40) {
        unsigned short u0 = Xb[(size_t)s0 * 40 + lane];
        unsigned short u1 = Xb[(size_t)s1 * 40 + lane];
        unsigned short u2 = Xb[(size_t)s2 * 40 + lane];
        unsigned short u3 = Xb[(size_t)s3 * 40 + lane];
        accA = fmaf(v0, __uint_as_float(((unsigned int)u0) << 16), accA);
        accB = fmaf(v1, __uint_as_float(((unsigned int)u1) << 16), accB);
        accA = fmaf(v2, __uint_as_float(((unsigned int)u2) << 16), accA);
        accB = fmaf(v3, __uint_as_float(((unsigned int)u3) << 16), accB);
      }
    }
    for (; j < cnt; ++j) {
      int src = __shfl(e_l.x, j);
      float val = __int_as_float(__shfl(e_l.y, j));
      if (lane < 40) {
        unsigned short u = Xb[(size_t)src * 40 + lane];
        accA = fmaf(val, __uint_as_float(((unsigned int)u) << 16), accA);
      }
    }
  }
  if (lane < 40) Y[(size_t)wid * 40 + lane] = accA + accB + bias[lane];
}

// ---------------------------------------------------------------------------
// Fused CRF row kernel, 4 edges per step: batched k/h0 gathers (8 loads in
// flight), 4 interleaved butterfly dot-reductions, one online-softmax update.
// ---------------------------------------------------------------------------
__global__ __launch_bounds__(256) void crf_fused_kernel(
    const int* __restrict__ row_ptr, const int2* __restrict__ edges,
    const float* __restrict__ Q, const unsigned short* __restrict__ Kb,
    const float* __restrict__ H0, const unsigned short* __restrict__ H0b,
    float* __restrict__ Y, const float* __restrict__ alpha_p,
    const float* __restrict__ beta_p, int nrows) {
  int wid = (blockIdx.x * 256 + threadIdx.x) >> 6;
  int lane = threadIdx.x & 63;
  if (wid >= nrows) return;
  int start = row_ptr[wid], end = row_ptr[wid + 1];
  float2 qv = *(const float2*)&Q[(size_t)wid * 128 + lane * 2];
  const float kScale = 0.08838834764831845f;  // 1/sqrt(128)
  float m = -3.4e38f, z = 0.f;
  float2 msg = make_float2(0.f, 0.f);
  for (int base = start; base < end; base += 64) {
    int cnt = end - base; if (cnt > 64) cnt = 64;
    int s_l = 0;
    if (lane < cnt) s_l = edges[base + lane].x;
    int j = 0;
    for (; j + 4 <= cnt; j += 4) {
      int s0 = __shfl(s_l, j + 0), s1 = __shfl(s_l, j + 1);
      int s2 = __shfl(s_l, j + 2), s3 = __shfl(s_l, j + 3);
      unsigned int k0 = *(const unsigned int*)(Kb + (size_t)s0 * 128 + lane * 2);
      unsigned int k1 = *(const unsigned int*)(Kb + (size_t)s1 * 128 + lane * 2);
      unsigned int k2 = *(const unsigned int*)(Kb + (size_t)s2 * 128 + lane * 2);
      unsigned int k3 = *(const unsigned int*)(Kb + (size_t)s3 * 128 + lane * 2);
      unsigned int h0 = *(const unsigned int*)(H0b + (size_t)s0 * 128 + lane * 2);
      unsigned int h1 = *(const unsigned int*)(H0b + (size_t)s1 * 128 + lane * 2);
      unsigned int h2 = *(const unsigned int*)(H0b + (size_t)s2 * 128 + lane * 2);
      unsigned int h3 = *(const unsigned int*)(H0b + (size_t)s3 * 128 + lane * 2);
      float p0 = qv.x * bf_lo(k0) + qv.y * bf_hi(k0);
      float p1 = qv.x * bf_lo(k1) + qv.y * bf_hi(k1);
      float p2 = qv.x * bf_lo(k2) + qv.y * bf_hi(k2);
      float p3 = qv.x * bf_lo(k3) + qv.y * bf_hi(k3);
      #pragma unroll
      for (int d = 32; d >= 1; d >>= 1) {
        p0 += __shfl_xor(p0, d);
        p1 += __shfl_xor(p1, d);
        p2 += __shfl_xor(p2, d);
        p3 += __shfl_xor(p3, d);
      }
      p0 *= kScale; p1 *= kScale; p2 *= kScale; p3 *= kScale;
      float pm = fmaxf(fmaxf(p0, p1), fmaxf(p2, p3));
      float mn = fmaxf(m, pm);
      float corr = __expf(m - mn);
      float w0 = __expf(p0 - mn), w1 = __expf(p1 - mn);
      float w2 = __expf(p2 - mn), w3 = __expf(p3 - mn);
      z = z * corr + (w0 + w1) + (w2 + w3);
      msg.x = msg.x * corr + w0 * bf_lo(h0) + w1 * bf_lo(h1)
                           + w2 * bf_lo(h2) + w3 * bf_lo(h3);
      msg.y = msg.y * corr + w0 * bf_hi(h0) + w1 * bf_hi(h1)
                           + w2 * bf_hi(h2) + w3 * bf_hi(h3);
      m = mn;
    }
    for (; j < cnt; ++j) {
      int src = __shfl(s_l, j);
      unsigned int ku = *(const unsigned int*)(Kb + (size_t)src * 128 + lane * 2);
      unsigned int hu = *(const unsigned int*)(H0b + (size_t)src * 128 + lane * 2);
      float p = qv.x * bf_lo(ku) + qv.y * bf_hi(ku);
      #pragma unroll
      for (int d = 32; d >= 1; d >>= 1) p += __shfl_xor(p, d);
      p *= kScale;
      float mn = fmaxf(m, p);
      float corr = __expf(m - mn);
      float w = __expf(p - mn);
      z = z * corr + w;
      msg.x = msg.x * corr + w * bf_lo(hu);
      msg.y = msg.y * corr + w * bf_hi(hu);
      m = mn;
    }
  }
  float alpha = *alpha_p, beta = *beta_p;
  float inv = 1.0f / (z + 1e-16f);
  float2 h0i = *(const float2*)&H0[(size_t)wid * 128 + lane * 2];
  float sc = 1.0f / (alpha + beta);
  float2 o;
  o.x = (alpha * h0i.x + beta * (msg.x * inv)) * sc;
  o.y = (alpha * h0i.y + beta * (msg.y * inv)) * sc;
  *(float2*)&Y[(size_t)wid * 128 + lane * 2] = o;
}

// Fused double unpool: crf_h[r] = h2[assign1[assign0[r]]] + h1[assign0[r]] + gcn[r]
__global__ __launch_bounds__(256) void unpool2_kernel(
    const float* __restrict__ H2, const float* __restrict__ H1,
    const float* __restrict__ Gcn, const int* __restrict__ assign0,
    const int* __restrict__ assign1, float* __restrict__ Y, int nrows) {
  int wid = (blockIdx.x * 256 + threadIdx.x) >> 6;
  int lane = threadIdx.x & 63;
  if (wid >= nrows) return;
  int a0 = assign0[wid];
  int a1 = assign1[a0];
  float2 v2 = *(const float2*)&H2[(size_t)a1 * 128 + lane * 2];
  float2 v1 = *(const float2*)&H1[(size_t)a0 * 128 + lane * 2];
  float2 vg = *(const float2*)&Gcn[(size_t)wid * 128 + lane * 2];
  float2 o = make_float2(v2.x + v1.x + vg.x, v2.y + v1.y + vg.y);
  *(float2*)&Y[(size_t)wid * 128 + lane * 2] = o;
}

}  // namespace

// ---------------------------------------------------------------------------
extern "C" void kernel_launch(void* const* d_in, const int* in_sizes, int n_in,
                              void* d_out, int out_size, void* d_ws, size_t ws_size,
                              hipStream_t stream) {
  const float* x       = (const float*)d_in[0];
  const int*   A0_idx  = (const int*)d_in[1];
  const float* A0_val  = (const float*)d_in[2];
  const int*   A1_idx  = (const int*)d_in[3];
  const int*   A2_idx  = (const int*)d_in[5];
  const int*   assign0 = (const int*)d_in[7];
  const int*   assign1 = (const int*)d_in[8];
  const int*   nwgt1   = (const int*)d_in[9];
  const int*   nwgt2   = (const int*)d_in[10];
  const float* gc1_W   = (const float*)d_in[11];
  const float* gc1_b   = (const float*)d_in[12];
  const float* gc2_W   = (const float*)d_in[13];
  const float* gc2_b   = (const float*)d_in[14];
  const float* c1_Wq   = (const float*)d_in[15];
  const float* c1_Wk   = (const float*)d_in[16];
  const float* c1_emb  = (const float*)d_in[17];
  const float* c1_al   = (const float*)d_in[18];
  const float* c1_be   = (const float*)d_in[19];
  const float* c2_Wq   = (const float*)d_in[20];
  const float* c2_Wk   = (const float*)d_in[21];
  const float* c2_emb  = (const float*)d_in[22];
  const float* c2_al   = (const float*)d_in[23];
  const float* c2_be   = (const float*)d_in[24];

  float* out_g = (float*)d_out;                      // [N0, 40]
  float* gcn_h = out_g + (size_t)kN0 * 40;           // [N0, 128]
  float* crf_h = gcn_h + (size_t)kN0 * 128;          // [N0, 128]

  // ---- workspace carving ----
  char* ws = (char*)d_ws;
  size_t off = 0;
  auto carve = [&](size_t bytes) -> void* {
    void* p = ws + off;
    off += (bytes + 511) & ~(size_t)511;
    return p;
  };
  int*   pos8     = (int*)carve((size_t)kTB8 * 4);         // 5.2 MB: counts -> scan -> cursors
  int*   row_ptr  = (int*)carve((size_t)(kTB + 1) * 4);
  int*   partials = (int*)carve(1024);
  int2*  edges    = (int2*)carve((size_t)kTE * 8);         // 17.8 MB
  float* h1_crf   = (float*)carve((size_t)kN1 * 128 * 4);  // 12.8 MB, long-lived
  char*  arena    = (char*)carve(51200000 + 4096);         // reused overlays
  // Overlays (byte offsets; lifetimes vs launch order):
  unsigned short* xWb   = (unsigned short*)(arena);              // [gc1 gemm .. gc1 spmm]
  float* h1_pool = (float*)(arena);                              // [pool1 .. qk1]
  float* h0_1    = (float*)(arena + 12800000);                   // [pool1 .. crf1]
  unsigned short* h0_1b = (unsigned short*)(arena + 25600000);   // [pool1 .. crf1]
  float* q1      = (float*)(arena + 32000000);                   // [qk1 .. crf1]
  unsigned short* k1b   = (unsigned short*)(arena + 44800000);   // [qk1 .. crf1]
  float* h2_pool = (float*)(arena);                              // [pool2 .. qk2]
  float* h0_2    = (float*)(arena + 3200000);                    // [pool2 .. crf2]
  unsigned short* h0_2b = (unsigned short*)(arena + 6400000);    // [pool2 .. crf2]
  float* q2      = (float*)(arena + 8000000);                    // [qk2 .. crf2]
  unsigned short* k2b   = (unsigned short*)(arena + 11200000);   // [qk2 .. crf2]
  float* h2_crf  = (float*)(arena + 12800000);                   // [crf2 .. unpool]
  unsigned short* hW2b  = (unsigned short*)(arena);              // [gemm40 .. spmm40]

  // ---- 1. batched CSR build for {A0, A1, A2, T0, T1} (XCD-local atomics) ----
  hipMemsetAsync(pos8, 0, (size_t)kTB8 * 4, stream);
  count_kernel<<<(kRankT + 255) / 256, 256, 0, stream>>>(A0_idx, A1_idx, A2_idx,
                                                         assign0, assign1, pos8);
  scan1_kernel<<<kNBLK, 256, 0, stream>>>(pos8, partials, kTB8);
  scan2_kernel<<<1, 256, 0, stream>>>(partials, kNBLK);
  scan3_kernel<<<(kTB8 + 255) / 256, 256, 0, stream>>>(pos8, partials, row_ptr, kTB8);
  place_kernel<<<(kRankT + 255) / 256, 256, 0, stream>>>(
      A0_idx, A0_val, A1_idx, A2_idx, assign0, assign1, pos8, edges);

  // ---- 2. gc1: h = relu(A0 @ (x W1) + b1) -> gcn_hidden ----
  gemm128_kernel<<<(kN0 + 63) / 64, 256, 0, stream>>>(x, gc1_W, nullptr, xWb, kN0);
  spmm128_kernel<true><<<(kN0 + 3) / 4, 256, 0, stream>>>(row_ptr, edges, xWb,
                                                          gcn_h, gc1_b, kN0, 1);
  // ---- 3. level-1 pool(+emb) + QK + CRF ----
  pool_emb_kernel<<<(kN1 + 3) / 4, 256, 0, stream>>>(row_ptr + kBO3, edges, gcn_h,
                                                     nwgt1, c1_emb, h1_pool, h0_1,
                                                     h0_1b, kN1);
  gemm128_qk_kernel<<<(kN1 + 63) / 64, 256, 0, stream>>>(h1_pool, c1_Wq, c1_Wk,
                                                         q1, k1b, kN1);
  crf_fused_kernel<<<(kN1 + 3) / 4, 256, 0, stream>>>(row_ptr + kBO1, edges, q1, k1b,
                                                      h0_1, h0_1b, h1_crf, c1_al,
                                                      c1_be, kN1);
  // ---- 4. level-2 pool(+emb) + QK + CRF ----
  pool_emb_kernel<<<(kN2 + 3) / 4, 256, 0, stream>>>(row_ptr + kBO4, edges, h1_crf,
                                                     nwgt2, c2_emb, h2_pool, h0_2,
                                                     h0_2b, kN2);
  gemm128_qk_kernel<<<(kN2 + 63) / 64, 256, 0, stream>>>(h2_pool, c2_Wq, c2_Wk,
                                                         q2, k2b, kN2);
  crf_fused_kernel<<<(kN2 + 3) / 4, 256, 0, stream>>>(row_ptr + kBO2, edges, q2, k2b,
                                                      h0_2, h0_2b, h2_crf, c2_al,
                                                      c2_be, kN2);
  // ---- 5. fused double unpool with skips -> crf_hidden ----
  unpool2_kernel<<<(kN0 + 3) / 4, 256, 0, stream>>>(h2_crf, h1_crf, gcn_h,
                                                    assign0, assign1, crf_h, kN0);
  // ---- 6. gc2: out = A0 @ (crf_hidden W2) + b2 ----
  gemm40_kernel<<<(kN0 + 63) / 64, 256, 0, stream>>>(crf_h, gc2_W, hW2b, kN0);
  spmm40_kernel<<<(kN0 + 3) / 4, 256, 0, stream>>>(row_ptr, edges, hW2b,
                                                   out_g, gc2_b, kN0);
}

// Round 2
// 742.094 us; speedup vs baseline: 1.1356x; 1.1356x over previous
//
#include <hip/hip_runtime.h>
#include <hip/hip_bf16.h>
#include <math.h>

namespace {

constexpr int kN0 = 100000, kN1 = 25000, kN2 = 6250;
constexpr int kE0 = 1600000, kE1 = 400000, kE2 = 100000;
// Concatenated-edge layout: [A0 | A1 | A2 | T0(assign0) | T1(assign1)]
constexpr int kEO1 = kE0;                   // 1,600,000
constexpr int kEO2 = kEO1 + kE1;            // 2,000,000
constexpr int kEO3 = kEO2 + kE2;            // 2,100,000
constexpr int kEO4 = kEO3 + kN0;            // 2,200,000
constexpr int kTE  = kEO4 + kN1;            // 2,225,000
// Concatenated-bin layout (destination node counts per graph)
constexpr int kBO1 = kN0;                   // A1 bins
constexpr int kBO2 = kBO1 + kN1;            // A2 bins
constexpr int kBO3 = kBO2 + kN2;            // T0 bins
constexpr int kBO4 = kBO3 + kN1;            // T1 bins
constexpr int kTB  = kBO4 + kN2;            // 162,500
constexpr int kNBLK = (kTB + 1023) / 1024;  // 159 scan blocks

__device__ __forceinline__ float bf_lo(unsigned int u) {
  return __uint_as_float(u << 16);
}
__device__ __forceinline__ float bf_hi(unsigned int u) {
  return __uint_as_float(u & 0xffff0000u);
}
__device__ __forceinline__ unsigned short f2bf(float f) {
  __hip_bfloat16 h = __float2bfloat16(f);
  return *reinterpret_cast<unsigned short*>(&h);
}

// edge id -> (dst, boff) for rank; full decode for place
__device__ __forceinline__ void edge_bin(
    int t, const int* a0i, const int* a1i, const int* a2i,
    const int* as0, const int* as1, int& dst, int& boff) {
  if (t < kEO1)      { dst = a0i[t];        boff = 0;    }
  else if (t < kEO2) { dst = a1i[t - kEO1]; boff = kBO1; }
  else if (t < kEO3) { dst = a2i[t - kEO2]; boff = kBO2; }
  else if (t < kEO4) { dst = as0[t - kEO3]; boff = kBO3; }
  else               { dst = as1[t - kEO4]; boff = kBO4; }
}

__device__ __forceinline__ void edge_decode(
    int t, const int* a0i, const float* a0v, const int* a1i, const int* a2i,
    const int* as0, const int* as1, int& dst, int& src, int& boff, float& val) {
  if (t < kEO1)      { dst = a0i[t]; src = a0i[kE0 + t]; val = a0v[t]; boff = 0; }
  else if (t < kEO2) { int e = t - kEO1; dst = a1i[e]; src = a1i[kE1 + e]; val = 1.0f; boff = kBO1; }
  else if (t < kEO3) { int e = t - kEO2; dst = a2i[e]; src = a2i[kE2 + e]; val = 1.0f; boff = kBO2; }
  else if (t < kEO4) { int e = t - kEO3; dst = as0[e]; src = e;            val = 1.0f; boff = kBO3; }
  else               { int e = t - kEO4; dst = as1[e]; src = e;            val = 1.0f; boff = kBO4; }
}

// ---------------------------------------------------------------------------
// CSR build: rank (atomic pass) -> scan -> place (no atomics).
// The rank dispatch is latency-bound with empty VALU pipes (round-0 PMC:
// VALUBusy 0.6%, HBM 10%), so the independent gc1 GEMM (x @ W1, pure VALU)
// is co-scheduled in the same dispatch as extra blocks: disjoint pipes,
// the GEMM hides under the atomic write-through latency.
// ---------------------------------------------------------------------------
constexpr int kRankT = (kTE + 3) / 4;                  // 556,250 threads
constexpr int kRankBlocks = (kRankT + 255) / 256;      // 2,174
constexpr int kGemmRows = 32;                          // 16.9KB LDS: no occ cap
constexpr int kGemmBlocks = (kN0 + kGemmRows - 1) / kGemmRows;  // 3,125

__global__ __launch_bounds__(256) void rank_gemm_kernel(
    const int* __restrict__ a0i, const int* __restrict__ a1i,
    const int* __restrict__ a2i, const int* __restrict__ as0,
    const int* __restrict__ as1, int* __restrict__ counts,
    int* __restrict__ rank,
    const float* __restrict__ A, const float* __restrict__ W,
    unsigned short* __restrict__ Cb, int M) {
  __shared__ float As[kGemmRows * 132];
  int t = threadIdx.x;
  if (blockIdx.x < kRankBlocks) {
    // ---- rank path: device-scope atomic histogram + rank store ----
    int tid = blockIdx.x * 256 + t;
    if (tid >= kRankT) return;
    int r[4];
    #pragma unroll
    for (int i = 0; i < 4; ++i) {
      int e = tid + i * kRankT;
      if (e < kTE) {
        int dst, boff;
        edge_bin(e, a0i, a1i, a2i, as0, as1, dst, boff);
        r[i] = atomicAdd(&counts[boff + dst], 1);
      }
    }
    #pragma unroll
    for (int i = 0; i < 4; ++i) {
      int e = tid + i * kRankT;
      if (e < kTE) rank[e] = r[i];
    }
    return;
  }
  // ---- gemm path: 32-row tile of Cb = bf16(A @ W), A[M,128], W[128,128] ----
  int row0 = (blockIdx.x - kRankBlocks) * kGemmRows;
  #pragma unroll
  for (int i = 0; i < 4; ++i) {
    int f = t + (i << 8);
    int r = f >> 5, c4 = (f & 31) << 2;
    int gr = row0 + r;
    float4 v = make_float4(0.f, 0.f, 0.f, 0.f);
    if (gr < M) v = *(const float4*)&A[(size_t)gr * 128 + c4];
    *(float4*)&As[r * 132 + c4] = v;
  }
  __syncthreads();
  int wcol = t & 31;
  int c4 = wcol << 2;
  int rsub = t >> 5;
  float4 acc[4];
  #pragma unroll
  for (int j = 0; j < 4; ++j) acc[j] = make_float4(0.f, 0.f, 0.f, 0.f);
  const float4* W4 = (const float4*)W;
  #pragma unroll 4
  for (int k = 0; k < 128; ++k) {
    float4 w = W4[k * 32 + wcol];
    #pragma unroll
    for (int j = 0; j < 4; ++j) {
      float a = As[(rsub + (j << 3)) * 132 + k];
      acc[j].x = fmaf(a, w.x, acc[j].x);
      acc[j].y = fmaf(a, w.y, acc[j].y);
      acc[j].z = fmaf(a, w.z, acc[j].z);
      acc[j].w = fmaf(a, w.w, acc[j].w);
    }
  }
  #pragma unroll
  for (int j = 0; j < 4; ++j) {
    int gr = row0 + rsub + (j << 3);
    if (gr < M) {
      ushort4 b;
      b.x = f2bf(acc[j].x); b.y = f2bf(acc[j].y);
      b.z = f2bf(acc[j].z); b.w = f2bf(acc[j].w);
      *(ushort4*)&Cb[(size_t)gr * 128 + c4] = b;
    }
  }
}

__global__ __launch_bounds__(256) void scan1_kernel(
    const int* __restrict__ in, int* __restrict__ out,
    int* __restrict__ partials, int n) {
  __shared__ int sdata[256];
  int t = threadIdx.x;
  int base = blockIdx.x * 1024;
  int v[4]; int s = 0;
  #pragma unroll
  for (int j = 0; j < 4; ++j) {
    int i = base + t * 4 + j;
    v[j] = (i < n) ? in[i] : 0;
    s += v[j];
  }
  sdata[t] = s;
  __syncthreads();
  for (int off = 1; off < 256; off <<= 1) {
    int x = (t >= off) ? sdata[t - off] : 0;
    __syncthreads();
    sdata[t] += x;
    __syncthreads();
  }
  int excl = sdata[t] - s;
  int run = 0;
  #pragma unroll
  for (int j = 0; j < 4; ++j) {
    int i = base + t * 4 + j;
    if (i < n) out[i] = excl + run;
    run += v[j];
  }
  if (t == 255) partials[blockIdx.x] = sdata[255];
}

__global__ __launch_bounds__(256) void scan2_kernel(int* partials, int nb) {
  __shared__ int sdata[256];
  int t = threadIdx.x;
  sdata[t] = (t < nb) ? partials[t] : 0;
  __syncthreads();
  for (int off = 1; off < 256; off <<= 1) {
    int x = (t >= off) ? sdata[t - off] : 0;
    __syncthreads();
    sdata[t] += x;
    __syncthreads();
  }
  if (t < nb) partials[t] = (t == 0) ? 0 : sdata[t - 1];
}

__global__ __launch_bounds__(256) void scan3_kernel(
    int* __restrict__ out, const int* __restrict__ partials, int n, int total) {
  int i = blockIdx.x * 256 + threadIdx.x;
  if (i < n) out[i] += partials[i >> 10];
  if (i == 0) out[n] = total;
}

__global__ __launch_bounds__(256) void place_kernel(
    const int* __restrict__ a0i, const float* __restrict__ a0v,
    const int* __restrict__ a1i, const int* __restrict__ a2i,
    const int* __restrict__ as0, const int* __restrict__ as1,
    const int* __restrict__ row_ptr, const int* __restrict__ rank,
    int2* __restrict__ edges) {
  int tid = blockIdx.x * 256 + threadIdx.x;
  if (tid >= kRankT) return;
  int pos[4]; int2 rec[4];
  #pragma unroll
  for (int i = 0; i < 4; ++i) {
    int t = tid + i * kRankT;
    if (t < kTE) {
      int dst, src, boff; float val;
      edge_decode(t, a0i, a0v, a1i, a2i, as0, as1, dst, src, boff, val);
      pos[i] = row_ptr[boff + dst] + rank[t];
      rec[i] = make_int2(src, __float_as_int(val));
    }
  }
  #pragma unroll
  for (int i = 0; i < 4; ++i) {
    int t = tid + i * kRankT;
    if (t < kTE) edges[pos[i]] = rec[i];
  }
}

// Fused Q/K projection: one LDS tile of A, two K-loops (Wq -> fp32, Wk -> bf16).
__global__ __launch_bounds__(256) void gemm128_qk_kernel(
    const float* __restrict__ A, const float* __restrict__ Wq,
    const float* __restrict__ Wk, float* __restrict__ Qf,
    unsigned short* __restrict__ Kb, int M) {
  __shared__ float As[64 * 132];
  int t = threadIdx.x;
  int row0 = blockIdx.x << 6;
  #pragma unroll
  for (int i = 0; i < 8; ++i) {
    int f = t + (i << 8);
    int r = f >> 5, c4 = (f & 31) << 2;
    int gr = row0 + r;
    float4 v = make_float4(0.f, 0.f, 0.f, 0.f);
    if (gr < M) v = *(const float4*)&A[(size_t)gr * 128 + c4];
    *(float4*)&As[r * 132 + c4] = v;
  }
  __syncthreads();
  int wcol = t & 31;
  int c4 = wcol << 2;
  int rsub = t >> 5;
  float4 acc[8];
  const float4* Wq4 = (const float4*)Wq;
  const float4* Wk4 = (const float4*)Wk;
  #pragma unroll
  for (int j = 0; j < 8; ++j) acc[j] = make_float4(0.f, 0.f, 0.f, 0.f);
  #pragma unroll 4
  for (int k = 0; k < 128; ++k) {
    float4 w = Wq4[k * 32 + wcol];
    #pragma unroll
    for (int j = 0; j < 8; ++j) {
      float a = As[(rsub + (j << 3)) * 132 + k];
      acc[j].x = fmaf(a, w.x, acc[j].x);
      acc[j].y = fmaf(a, w.y, acc[j].y);
      acc[j].z = fmaf(a, w.z, acc[j].z);
      acc[j].w = fmaf(a, w.w, acc[j].w);
    }
  }
  #pragma unroll
  for (int j = 0; j < 8; ++j) {
    int gr = row0 + rsub + (j << 3);
    if (gr < M) *(float4*)&Qf[(size_t)gr * 128 + c4] = acc[j];
  }
  #pragma unroll
  for (int j = 0; j < 8; ++j) acc[j] = make_float4(0.f, 0.f, 0.f, 0.f);
  #pragma unroll 4
  for (int k = 0; k < 128; ++k) {
    float4 w = Wk4[k * 32 + wcol];
    #pragma unroll
    for (int j = 0; j < 8; ++j) {
      float a = As[(rsub + (j << 3)) * 132 + k];
      acc[j].x = fmaf(a, w.x, acc[j].x);
      acc[j].y = fmaf(a, w.y, acc[j].y);
      acc[j].z = fmaf(a, w.z, acc[j].z);
      acc[j].w = fmaf(a, w.w, acc[j].w);
    }
  }
  #pragma unroll
  for (int j = 0; j < 8; ++j) {
    int gr = row0 + rsub + (j << 3);
    if (gr < M) {
      ushort4 b;
      b.x = f2bf(acc[j].x); b.y = f2bf(acc[j].y);
      b.z = f2bf(acc[j].z); b.w = f2bf(acc[j].w);
      *(ushort4*)&Kb[(size_t)gr * 128 + c4] = b;
    }
  }
}

// C[M,40] = A[M,128] @ W[128,40], bf16 output (consumed by gathers only)
__global__ __launch_bounds__(256) void gemm40_kernel(
    const float* __restrict__ A, const float* __restrict__ W,
    unsigned short* __restrict__ Cb, int M) {
  __shared__ float Ws[128 * 40];
  __shared__ float As[64 * 132];
  int t = threadIdx.x;
  int row0 = blockIdx.x << 6;
  #pragma unroll
  for (int i = 0; i < 5; ++i)
    ((float4*)Ws)[t + i * 256] = ((const float4*)W)[t + i * 256];
  #pragma unroll
  for (int i = 0; i < 8; ++i) {
    int f = t + (i << 8);
    int r = f >> 5, c4 = (f & 31) << 2;
    int gr = row0 + r;
    float4 v = make_float4(0.f, 0.f, 0.f, 0.f);
    if (gr < M) v = *(const float4*)&A[(size_t)gr * 128 + c4];
    *(float4*)&As[r * 132 + c4] = v;
  }
  __syncthreads();
  int r = t >> 2;
  int cg = (t & 3) * 10;
  float acc[10];
  #pragma unroll
  for (int j = 0; j < 10; ++j) acc[j] = 0.f;
  for (int k = 0; k < 128; ++k) {
    float a = As[r * 132 + k];
    #pragma unroll
    for (int j = 0; j < 10; ++j) acc[j] = fmaf(a, Ws[k * 40 + cg + j], acc[j]);
  }
  int gr = row0 + r;
  if (gr < M) {
    #pragma unroll
    for (int j = 0; j < 10; ++j) Cb[(size_t)gr * 40 + cg + j] = f2bf(acc[j]);
  }
}

// ---------------------------------------------------------------------------
// Pull-SpMM over CSR: one wave per dst row, 128 cols (2/lane), 4-way MLP.
// ---------------------------------------------------------------------------
template <bool BF16>
__global__ __launch_bounds__(256) void spmm128_kernel(
    const int* __restrict__ row_ptr, const int2* __restrict__ edges,
    const void* __restrict__ Xv, float* __restrict__ Y,
    const float* __restrict__ bias, int nrows, int do_relu) {
  int wid = (blockIdx.x * 256 + threadIdx.x) >> 6;
  int lane = threadIdx.x & 63;
  if (wid >= nrows) return;
  int start = row_ptr[wid], end = row_ptr[wid + 1];
  const unsigned short* Xb = (const unsigned short*)Xv;
  const float* Xf = (const float*)Xv;
  float2 accA = make_float2(0.f, 0.f), accB = make_float2(0.f, 0.f);
  for (int base = start; base < end; base += 64) {
    int cnt = end - base; if (cnt > 64) cnt = 64;
    int2 e_l = make_int2(0, 0);
    if (lane < cnt) e_l = edges[base + lane];
    int j = 0;
    for (; j + 4 <= cnt; j += 4) {
      int s0 = __shfl(e_l.x, j + 0), s1 = __shfl(e_l.x, j + 1);
      int s2 = __shfl(e_l.x, j + 2), s3 = __shfl(e_l.x, j + 3);
      float v0 = __int_as_float(__shfl(e_l.y, j + 0));
      float v1 = __int_as_float(__shfl(e_l.y, j + 1));
      float v2 = __int_as_float(__shfl(e_l.y, j + 2));
      float v3 = __int_as_float(__shfl(e_l.y, j + 3));
      if (BF16) {
        unsigned int u0 = *(const unsigned int*)(Xb + (size_t)s0 * 128 + lane * 2);
        unsigned int u1 = *(const unsigned int*)(Xb + (size_t)s1 * 128 + lane * 2);
        unsigned int u2 = *(const unsigned int*)(Xb + (size_t)s2 * 128 + lane * 2);
        unsigned int u3 = *(const unsigned int*)(Xb + (size_t)s3 * 128 + lane * 2);
        accA.x = fmaf(v0, bf_lo(u0), accA.x); accA.y = fmaf(v0, bf_hi(u0), accA.y);
        accB.x = fmaf(v1, bf_lo(u1), accB.x); accB.y = fmaf(v1, bf_hi(u1), accB.y);
        accA.x = fmaf(v2, bf_lo(u2), accA.x); accA.y = fmaf(v2, bf_hi(u2), accA.y);
        accB.x = fmaf(v3, bf_lo(u3), accB.x); accB.y = fmaf(v3, bf_hi(u3), accB.y);
      } else {
        float2 x0 = *(const float2*)(Xf + (size_t)s0 * 128 + lane * 2);
        float2 x1 = *(const float2*)(Xf + (size_t)s1 * 128 + lane * 2);
        float2 x2 = *(const float2*)(Xf + (size_t)s2 * 128 + lane * 2);
        float2 x3 = *(const float2*)(Xf + (size_t)s3 * 128 + lane * 2);
        accA.x = fmaf(v0, x0.x, accA.x); accA.y = fmaf(v0, x0.y, accA.y);
        accB.x = fmaf(v1, x1.x, accB.x); accB.y = fmaf(v1, x1.y, accB.y);
        accA.x = fmaf(v2, x2.x, accA.x); accA.y = fmaf(v2, x2.y, accA.y);
        accB.x = fmaf(v3, x3.x, accB.x); accB.y = fmaf(v3, x3.y, accB.y);
      }
    }
    for (; j < cnt; ++j) {
      int src = __shfl(e_l.x, j);
      float val = __int_as_float(__shfl(e_l.y, j));
      if (BF16) {
        unsigned int u = *(const unsigned int*)(Xb + (size_t)src * 128 + lane * 2);
        accA.x = fmaf(val, bf_lo(u), accA.x);
        accA.y = fmaf(val, bf_hi(u), accA.y);
      } else {
        float2 xv = *(const float2*)(Xf + (size_t)src * 128 + lane * 2);
        accA.x = fmaf(val, xv.x, accA.x);
        accA.y = fmaf(val, xv.y, accA.y);
      }
    }
  }
  float2 acc = make_float2(accA.x + accB.x, accA.y + accB.y);
  if (bias) { acc.x += bias[lane * 2]; acc.y += bias[lane * 2 + 1]; }
  if (do_relu) { acc.x = fmaxf(acc.x, 0.f); acc.y = fmaxf(acc.y, 0.f); }
  *(float2*)&Y[(size_t)wid * 128 + lane * 2] = acc;
}

// Pool (T-graph pull sum) fused with nwgt-embedding add, 4-way MLP.
__global__ __launch_bounds__(256) void pool_emb_kernel(
    const int* __restrict__ row_ptr, const int2* __restrict__ edges,
    const float* __restrict__ X, const int* __restrict__ nwgt,
    const float* __restrict__ emb, float* __restrict__ Hpool,
    float* __restrict__ H0, unsigned short* __restrict__ H0b, int nrows) {
  int wid = (blockIdx.x * 256 + threadIdx.x) >> 6;
  int lane = threadIdx.x & 63;
  if (wid >= nrows) return;
  int start = row_ptr[wid], end = row_ptr[wid + 1];
  float2 accA = make_float2(0.f, 0.f), accB = make_float2(0.f, 0.f);
  for (int base = start; base < end; base += 64) {
    int cnt = end - base; if (cnt > 64) cnt = 64;
    int s_l = 0;
    if (lane < cnt) s_l = edges[base + lane].x;
    int j = 0;
    for (; j + 4 <= cnt; j += 4) {
      int s0 = __shfl(s_l, j + 0), s1 = __shfl(s_l, j + 1);
      int s2 = __shfl(s_l, j + 2), s3 = __shfl(s_l, j + 3);
      float2 x0 = *(const float2*)&X[(size_t)s0 * 128 + lane * 2];
      float2 x1 = *(const float2*)&X[(size_t)s1 * 128 + lane * 2];
      float2 x2 = *(const float2*)&X[(size_t)s2 * 128 + lane * 2];
      float2 x3 = *(const float2*)&X[(size_t)s3 * 128 + lane * 2];
      accA.x += x0.x + x2.x; accA.y += x0.y + x2.y;
      accB.x += x1.x + x3.x; accB.y += x1.y + x3.y;
    }
    for (; j < cnt; ++j) {
      int src = __shfl(s_l, j);
      float2 xv = *(const float2*)&X[(size_t)src * 128 + lane * 2];
      accA.x += xv.x; accA.y += xv.y;
    }
  }
  float2 acc = make_float2(accA.x + accB.x, accA.y + accB.y);
  *(float2*)&Hpool[(size_t)wid * 128 + lane * 2] = acc;
  float2 ev = *(const float2*)&emb[(size_t)nwgt[wid] * 128 + lane * 2];
  float2 h0 = make_float2(acc.x + ev.x, acc.y + ev.y);
  *(float2*)&H0[(size_t)wid * 128 + lane * 2] = h0;
  unsigned int packed = ((unsigned int)f2bf(h0.x)) | (((unsigned int)f2bf(h0.y)) << 16);
  *(unsigned int*)(H0b + (size_t)wid * 128 + lane * 2) = packed;
}

__global__ __launch_bounds__(256) void spmm40_kernel(
    const int* __restrict__ row_ptr, const int2* __restrict__ edges,
    const unsigned short* __restrict__ Xb, float* __restrict__ Y,
    const float* __restrict__ bias, int nrows) {
  int wid = (blockIdx.x * 256 + threadIdx.x) >> 6;
  int lane = threadIdx.x & 63;
  if (wid >= nrows) return;
  int start = row_ptr[wid], end = row_ptr[wid + 1];
  float accA = 0.f, accB = 0.f;
  for (int base = start; base < end; base += 64) {
    int cnt = end - base; if (cnt > 64) cnt = 64;
    int2 e_l = make_int2(0, 0);
    if (lane < cnt) e_l = edges[base + lane];
    int j = 0;
    for (; j + 4 <= cnt; j += 4) {
      int s0 = __shfl(e_l.x, j + 0), s1 = __shfl(e_l.x, j + 1);
      int s2 = __shfl(e_l.x, j + 2), s3 = __shfl(e_l.x, j + 3);
      float v0 = __int_as_float(__shfl(e_l.y, j + 0));
      float v1 = __int_as_float(__shfl(e_l.y, j + 1));
      float v2 = __int_as_float(__shfl(e_l.y, j + 2));
      float v3 = __int_as_float(__shfl(e_l.y, j + 3));
      if (lane < 40) {
        unsigned short u0 = Xb[(size_t)s0 * 40 + lane];
        unsigned short u1 = Xb[(size_t)s1 * 40 + lane];
        unsigned short u2 = Xb[(size_t)s2 * 40 + lane];
        unsigned short u3 = Xb[(size_t)s3 * 40 + lane];
        accA = fmaf(v0, __uint_as_float(((unsigned int)u0) << 16), accA);
        accB = fmaf(v1, __uint_as_float(((unsigned int)u1) << 16), accB);
        accA = fmaf(v2, __uint_as_float(((unsigned int)u2) << 16), accA);
        accB = fmaf(v3, __uint_as_float(((unsigned int)u3) << 16), accB);
      }
    }
    for (; j < cnt; ++j) {
      int src = __shfl(e_l.x, j);
      float val = __int_as_float(__shfl(e_l.y, j));
      if (lane < 40) {
        unsigned short u = Xb[(size_t)src * 40 + lane];
        accA = fmaf(val, __uint_as_float(((unsigned int)u) << 16), accA);
      }
    }
  }
  if (lane < 40) Y[(size_t)wid * 40 + lane] = accA + accB + bias[lane];
}

// ---------------------------------------------------------------------------
// Fused CRF row kernel, 4 edges per step: batched k/h0 gathers (8 loads in
// flight), 4 interleaved butterfly dot-reductions, one online-softmax update.
// ---------------------------------------------------------------------------
__global__ __launch_bounds__(256) void crf_fused_kernel(
    const int* __restrict__ row_ptr, const int2* __restrict__ edges,
    const float* __restrict__ Q, const unsigned short* __restrict__ Kb,
    const float* __restrict__ H0, const unsigned short* __restrict__ H0b,
    float* __restrict__ Y, const float* __restrict__ alpha_p,
    const float* __restrict__ beta_p, int nrows) {
  int wid = (blockIdx.x * 256 + threadIdx.x) >> 6;
  int lane = threadIdx.x & 63;
  if (wid >= nrows) return;
  int start = row_ptr[wid], end = row_ptr[wid + 1];
  float2 qv = *(const float2*)&Q[(size_t)wid * 128 + lane * 2];
  const float kScale = 0.08838834764831845f;  // 1/sqrt(128)
  float m = -3.4e38f, z = 0.f;
  float2 msg = make_float2(0.f, 0.f);
  for (int base = start; base < end; base += 64) {
    int cnt = end - base; if (cnt > 64) cnt = 64;
    int s_l = 0;
    if (lane < cnt) s_l = edges[base + lane].x;
    int j = 0;
    for (; j + 4 <= cnt; j += 4) {
      int s0 = __shfl(s_l, j + 0), s1 = __shfl(s_l, j + 1);
      int s2 = __shfl(s_l, j + 2), s3 = __shfl(s_l, j + 3);
      unsigned int k0 = *(const unsigned int*)(Kb + (size_t)s0 * 128 + lane * 2);
      unsigned int k1 = *(const unsigned int*)(Kb + (size_t)s1 * 128 + lane * 2);
      unsigned int k2 = *(const unsigned int*)(Kb + (size_t)s2 * 128 + lane * 2);
      unsigned int k3 = *(const unsigned int*)(Kb + (size_t)s3 * 128 + lane * 2);
      unsigned int h0 = *(const unsigned int*)(H0b + (size_t)s0 * 128 + lane * 2);
      unsigned int h1 = *(const unsigned int*)(H0b + (size_t)s1 * 128 + lane * 2);
      unsigned int h2 = *(const unsigned int*)(H0b + (size_t)s2 * 128 + lane * 2);
      unsigned int h3 = *(const unsigned int*)(H0b + (size_t)s3 * 128 + lane * 2);
      float p0 = qv.x * bf_lo(k0) + qv.y * bf_hi(k0);
      float p1 = qv.x * bf_lo(k1) + qv.y * bf_hi(k1);
      float p2 = qv.x * bf_lo(k2) + qv.y * bf_hi(k2);
      float p3 = qv.x * bf_lo(k3) + qv.y * bf_hi(k3);
      #pragma unroll
      for (int d = 32; d >= 1; d >>= 1) {
        p0 += __shfl_xor(p0, d);
        p1 += __shfl_xor(p1, d);
        p2 += __shfl_xor(p2, d);
        p3 += __shfl_xor(p3, d);
      }
      p0 *= kScale; p1 *= kScale; p2 *= kScale; p3 *= kScale;
      float pm = fmaxf(fmaxf(p0, p1), fmaxf(p2, p3));
      float mn = fmaxf(m, pm);
      float corr = __expf(m - mn);
      float w0 = __expf(p0 - mn), w1 = __expf(p1 - mn);
      float w2 = __expf(p2 - mn), w3 = __expf(p3 - mn);
      z = z * corr + (w0 + w1) + (w2 + w3);
      msg.x = msg.x * corr + w0 * bf_lo(h0) + w1 * bf_lo(h1)
                           + w2 * bf_lo(h2) + w3 * bf_lo(h3);
      msg.y = msg.y * corr + w0 * bf_hi(h0) + w1 * bf_hi(h1)
                           + w2 * bf_hi(h2) + w3 * bf_hi(h3);
      m = mn;
    }
    for (; j < cnt; ++j) {
      int src = __shfl(s_l, j);
      unsigned int ku = *(const unsigned int*)(Kb + (size_t)src * 128 + lane * 2);
      unsigned int hu = *(const unsigned int*)(H0b + (size_t)src * 128 + lane * 2);
      float p = qv.x * bf_lo(ku) + qv.y * bf_hi(ku);
      #pragma unroll
      for (int d = 32; d >= 1; d >>= 1) p += __shfl_xor(p, d);
      p *= kScale;
      float mn = fmaxf(m, p);
      float corr = __expf(m - mn);
      float w = __expf(p - mn);
      z = z * corr + w;
      msg.x = msg.x * corr + w * bf_lo(hu);
      msg.y = msg.y * corr + w * bf_hi(hu);
      m = mn;
    }
  }
  float alpha = *alpha_p, beta = *beta_p;
  float inv = 1.0f / (z + 1e-16f);
  float2 h0i = *(const float2*)&H0[(size_t)wid * 128 + lane * 2];
  float sc = 1.0f / (alpha + beta);
  float2 o;
  o.x = (alpha * h0i.x + beta * (msg.x * inv)) * sc;
  o.y = (alpha * h0i.y + beta * (msg.y * inv)) * sc;
  *(float2*)&Y[(size_t)wid * 128 + lane * 2] = o;
}

// Fused double unpool: crf_h[r] = h2[assign1[assign0[r]]] + h1[assign0[r]] + gcn[r]
__global__ __launch_bounds__(256) void unpool2_kernel(
    const float* __restrict__ H2, const float* __restrict__ H1,
    const float* __restrict__ Gcn, const int* __restrict__ assign0,
    const int* __restrict__ assign1, float* __restrict__ Y, int nrows) {
  int wid = (blockIdx.x * 256 + threadIdx.x) >> 6;
  int lane = threadIdx.x & 63;
  if (wid >= nrows) return;
  int a0 = assign0[wid];
  int a1 = assign1[a0];
  float2 v2 = *(const float2*)&H2[(size_t)a1 * 128 + lane * 2];
  float2 v1 = *(const float2*)&H1[(size_t)a0 * 128 + lane * 2];
  float2 vg = *(const float2*)&Gcn[(size_t)wid * 128 + lane * 2];
  float2 o = make_float2(v2.x + v1.x + vg.x, v2.y + v1.y + vg.y);
  *(float2*)&Y[(size_t)wid * 128 + lane * 2] = o;
}

}  // namespace

// ---------------------------------------------------------------------------
extern "C" void kernel_launch(void* const* d_in, const int* in_sizes, int n_in,
                              void* d_out, int out_size, void* d_ws, size_t ws_size,
                              hipStream_t stream) {
  const float* x       = (const float*)d_in[0];
  const int*   A0_idx  = (const int*)d_in[1];
  const float* A0_val  = (const float*)d_in[2];
  const int*   A1_idx  = (const int*)d_in[3];
  const int*   A2_idx  = (const int*)d_in[5];
  const int*   assign0 = (const int*)d_in[7];
  const int*   assign1 = (const int*)d_in[8];
  const int*   nwgt1   = (const int*)d_in[9];
  const int*   nwgt2   = (const int*)d_in[10];
  const float* gc1_W   = (const float*)d_in[11];
  const float* gc1_b   = (const float*)d_in[12];
  const float* gc2_W   = (const float*)d_in[13];
  const float* gc2_b   = (const float*)d_in[14];
  const float* c1_Wq   = (const float*)d_in[15];
  const float* c1_Wk   = (const float*)d_in[16];
  const float* c1_emb  = (const float*)d_in[17];
  const float* c1_al   = (const float*)d_in[18];
  const float* c1_be   = (const float*)d_in[19];
  const float* c2_Wq   = (const float*)d_in[20];
  const float* c2_Wk   = (const float*)d_in[21];
  const float* c2_emb  = (const float*)d_in[22];
  const float* c2_al   = (const float*)d_in[23];
  const float* c2_be   = (const float*)d_in[24];

  float* out_g = (float*)d_out;                      // [N0, 40]
  float* gcn_h = out_g + (size_t)kN0 * 40;           // [N0, 128]
  float* crf_h = gcn_h + (size_t)kN0 * 128;          // [N0, 128]

  // ---- workspace carving ----
  char* ws = (char*)d_ws;
  size_t off = 0;
  auto carve = [&](size_t bytes) -> void* {
    void* p = ws + off;
    off += (bytes + 511) & ~(size_t)511;
    return p;
  };
  int*   counts   = (int*)carve((size_t)(kTB + 1) * 4);
  int*   row_ptr  = (int*)carve((size_t)(kTB + 1) * 4);
  int*   partials = (int*)carve(1024);
  int*   rank     = (int*)carve((size_t)kTE * 4);          // 8.9 MB
  int2*  edges    = (int2*)carve((size_t)kTE * 8);         // 17.8 MB
  float* h1_crf   = (float*)carve((size_t)kN1 * 128 * 4);  // 12.8 MB, long-lived
  char*  arena    = (char*)carve(51200000 + 4096);         // reused overlays
  // Overlays (byte offsets; lifetimes vs launch order):
  unsigned short* xWb   = (unsigned short*)(arena);              // [gc1 gemm .. gc1 spmm]
  float* h1_pool = (float*)(arena);                              // [pool1 .. qk1]
  float* h0_1    = (float*)(arena + 12800000);                   // [pool1 .. crf1]
  unsigned short* h0_1b = (unsigned short*)(arena + 25600000);   // [pool1 .. crf1]
  float* q1      = (float*)(arena + 32000000);                   // [qk1 .. crf1]
  unsigned short* k1b   = (unsigned short*)(arena + 44800000);   // [qk1 .. crf1]
  float* h2_pool = (float*)(arena);                              // [pool2 .. qk2]
  float* h0_2    = (float*)(arena + 3200000);                    // [pool2 .. crf2]
  unsigned short* h0_2b = (unsigned short*)(arena + 6400000);    // [pool2 .. crf2]
  float* q2      = (float*)(arena + 8000000);                    // [qk2 .. crf2]
  unsigned short* k2b   = (unsigned short*)(arena + 11200000);   // [qk2 .. crf2]
  float* h2_crf  = (float*)(arena + 12800000);                   // [crf2 .. unpool]
  unsigned short* hW2b  = (unsigned short*)(arena);              // [gemm40 .. spmm40]

  // NOTE: xWb overlays h1_pool/h0_1 region; xWb is written by the fused
  // rank_gemm kernel and last read by spmm128 (gc1), which completes before
  // pool_emb writes h1_pool. Lifetimes disjoint, same as round-0 layout.

  // ---- 1. CSR build; gc1 GEMM co-scheduled in the rank dispatch ----
  hipMemsetAsync(counts, 0, (size_t)(kTB + 1) * 4, stream);
  rank_gemm_kernel<<<kRankBlocks + kGemmBlocks, 256, 0, stream>>>(
      A0_idx, A1_idx, A2_idx, assign0, assign1, counts, rank,
      x, gc1_W, xWb, kN0);
  scan1_kernel<<<kNBLK, 256, 0, stream>>>(counts, row_ptr, partials, kTB);
  scan2_kernel<<<1, 256, 0, stream>>>(partials, kNBLK);
  scan3_kernel<<<(kTB + 255) / 256, 256, 0, stream>>>(row_ptr, partials, kTB, kTE);
  place_kernel<<<(kRankT + 255) / 256, 256, 0, stream>>>(
      A0_idx, A0_val, A1_idx, A2_idx, assign0, assign1, row_ptr, rank, edges);

  // ---- 2. gc1 aggregation: h = relu(A0 @ (x W1) + b1) -> gcn_hidden ----
  spmm128_kernel<true><<<(kN0 + 3) / 4, 256, 0, stream>>>(row_ptr, edges, xWb,
                                                          gcn_h, gc1_b, kN0, 1);
  // ---- 3. level-1 pool(+emb) + QK + CRF ----
  pool_emb_kernel<<<(kN1 + 3) / 4, 256, 0, stream>>>(row_ptr + kBO3, edges, gcn_h,
                                                     nwgt1, c1_emb, h1_pool, h0_1,
                                                     h0_1b, kN1);
  gemm128_qk_kernel<<<(kN1 + 63) / 64, 256, 0, stream>>>(h1_pool, c1_Wq, c1_Wk,
                                                         q1, k1b, kN1);
  crf_fused_kernel<<<(kN1 + 3) / 4, 256, 0, stream>>>(row_ptr + kBO1, edges, q1, k1b,
                                                      h0_1, h0_1b, h1_crf, c1_al,
                                                      c1_be, kN1);
  // ---- 4. level-2 pool(+emb) + QK + CRF ----
  pool_emb_kernel<<<(kN2 + 3) / 4, 256, 0, stream>>>(row_ptr + kBO4, edges, h1_crf,
                                                     nwgt2, c2_emb, h2_pool, h0_2,
                                                     h0_2b, kN2);
  gemm128_qk_kernel<<<(kN2 + 63) / 64, 256, 0, stream>>>(h2_pool, c2_Wq, c2_Wk,
                                                         q2, k2b, kN2);
  crf_fused_kernel<<<(kN2 + 3) / 4, 256, 0, stream>>>(row_ptr + kBO2, edges, q2, k2b,
                                                      h0_2, h0_2b, h2_crf, c2_al,
                                                      c2_be, kN2);
  // ---- 5. fused double unpool with skips -> crf_hidden ----
  unpool2_kernel<<<(kN0 + 3) / 4, 256, 0, stream>>>(h2_crf, h1_crf, gcn_h,
                                                    assign0, assign1, crf_h, kN0);
  // ---- 6. gc2: out = A0 @ (crf_hidden W2) + b2 ----
  gemm40_kernel<<<(kN0 + 63) / 64, 256, 0, stream>>>(crf_h, gc2_W, hW2b, kN0);
  spmm40_kernel<<<(kN0 + 3) / 4, 256, 0, stream>>>(row_ptr, edges, hW2b,
                                                   out_g, gc2_b, kN0);
}

// Round 3
// 711.003 us; speedup vs baseline: 1.1852x; 1.0437x over previous
//
#include <hip/hip_runtime.h>
#include <hip/hip_bf16.h>
#include <math.h>

namespace {

constexpr int kN0 = 100000, kN1 = 25000, kN2 = 6250;
constexpr int kE0 = 1600000, kE1 = 400000, kE2 = 100000;
// Concatenated-edge layout: [A0 | A1 | A2 | T0(assign0) | T1(assign1)]
constexpr int kEO1 = kE0;                   // 1,600,000
constexpr int kEO2 = kEO1 + kE1;            // 2,000,000
constexpr int kEO3 = kEO2 + kE2;            // 2,100,000
constexpr int kEO4 = kEO3 + kN0;            // 2,200,000
constexpr int kTE  = kEO4 + kN1;            // 2,225,000
// Concatenated-bin layout (destination node counts per graph)
constexpr int kBO1 = kN0;                   // A1 bins
constexpr int kBO2 = kBO1 + kN1;            // A2 bins
constexpr int kBO3 = kBO2 + kN2;            // T0 bins
constexpr int kBO4 = kBO3 + kN1;            // T1 bins
constexpr int kTB  = kBO4 + kN2;            // 162,500 total bins

// ---- two-level bucket sort geometry ----
// Coarse bucket = bin >> 8 (256 fine bins per bucket).
constexpr int kNCB = (kTB + 255) / 256;     // 635 coarse buckets
constexpr int kEPB = 8192;                  // edges per hist/scatter block
constexpr int kNBA = (kTE + kEPB - 1) / kEPB;  // 272 blocks
constexpr int kGN  = kNCB * kNBA;           // 172,720 (bucket-major G matrix)
constexpr int kNBLK_G = (kGN + 1023) / 1024;   // 169 scan blocks (<=256 ok)

constexpr int kGemmRows = 32;               // fused gemm tile rows
constexpr int kGemmBlocks = (kN0 + kGemmRows - 1) / kGemmRows;  // 3,125

__device__ __forceinline__ float bf_lo(unsigned int u) {
  return __uint_as_float(u << 16);
}
__device__ __forceinline__ float bf_hi(unsigned int u) {
  return __uint_as_float(u & 0xffff0000u);
}
__device__ __forceinline__ unsigned short f2bf(float f) {
  __hip_bfloat16 h = __float2bfloat16(f);
  return *reinterpret_cast<unsigned short*>(&h);
}

// edge id -> (dst, boff) for hist; full decode for scatter
__device__ __forceinline__ void edge_bin(
    int t, const int* a0i, const int* a1i, const int* a2i,
    const int* as0, const int* as1, int& dst, int& boff) {
  if (t < kEO1)      { dst = a0i[t];        boff = 0;    }
  else if (t < kEO2) { dst = a1i[t - kEO1]; boff = kBO1; }
  else if (t < kEO3) { dst = a2i[t - kEO2]; boff = kBO2; }
  else if (t < kEO4) { dst = as0[t - kEO3]; boff = kBO3; }
  else               { dst = as1[t - kEO4]; boff = kBO4; }
}

__device__ __forceinline__ void edge_decode(
    int t, const int* a0i, const float* a0v, const int* a1i, const int* a2i,
    const int* as0, const int* as1, int& dst, int& src, int& boff, float& val) {
  if (t < kEO1)      { dst = a0i[t]; src = a0i[kE0 + t]; val = a0v[t]; boff = 0; }
  else if (t < kEO2) { int e = t - kEO1; dst = a1i[e]; src = a1i[kE1 + e]; val = 1.0f; boff = kBO1; }
  else if (t < kEO3) { int e = t - kEO2; dst = a2i[e]; src = a2i[kE2 + e]; val = 1.0f; boff = kBO2; }
  else if (t < kEO4) { int e = t - kEO3; dst = as0[e]; src = e;            val = 1.0f; boff = kBO3; }
  else               { int e = t - kEO4; dst = as1[e]; src = e;            val = 1.0f; boff = kBO4; }
}

// ---------------------------------------------------------------------------
// CSR build via two-level bucket sort — ZERO global atomics.
//  hist:    per-block LDS histogram over 635 coarse buckets -> G[bucket][blk]
//  scan:    exclusive scan of G (bucket-major) = disjoint chunk bases;
//           G[b*kNBA] = bucketStart[b].
//  scatter: replay with LDS cursors; edges land in the block's own chunk
//           (runs of ~13 edges -> L2 write-combining, no per-store sectors).
//  finesort: one block per bucket; LDS count/scan of 256 fine bins ->
//           row_ptr + final edge placement, all writes within a 28KB window.
// Replaces rank(100us, 2.2M device atomics) + place(90us, scattered stores).
// ---------------------------------------------------------------------------

__global__ __launch_bounds__(256) void hist_kernel(
    const int* __restrict__ a0i, const int* __restrict__ a1i,
    const int* __restrict__ a2i, const int* __restrict__ as0,
    const int* __restrict__ as1, int* __restrict__ G) {
  __shared__ int hist[kNCB];
  int t = threadIdx.x;
  for (int i = t; i < kNCB; i += 256) hist[i] = 0;
  __syncthreads();
  int base = blockIdx.x * kEPB;
  #pragma unroll 4
  for (int j = 0; j < kEPB / 256; ++j) {
    int e = base + j * 256 + t;
    if (e < kTE) {
      int dst, boff;
      edge_bin(e, a0i, a1i, a2i, as0, as1, dst, boff);
      atomicAdd(&hist[(boff + dst) >> 8], 1);
    }
  }
  __syncthreads();
  for (int i = t; i < kNCB; i += 256)
    G[(size_t)i * kNBA + blockIdx.x] = hist[i];
}

__global__ __launch_bounds__(256) void scan1_kernel(
    const int* __restrict__ in, int* __restrict__ out,
    int* __restrict__ partials, int n) {
  __shared__ int sdata[256];
  int t = threadIdx.x;
  int base = blockIdx.x * 1024;
  int v[4]; int s = 0;
  #pragma unroll
  for (int j = 0; j < 4; ++j) {
    int i = base + t * 4 + j;
    v[j] = (i < n) ? in[i] : 0;
    s += v[j];
  }
  sdata[t] = s;
  __syncthreads();
  for (int off = 1; off < 256; off <<= 1) {
    int x = (t >= off) ? sdata[t - off] : 0;
    __syncthreads();
    sdata[t] += x;
    __syncthreads();
  }
  int excl = sdata[t] - s;
  int run = 0;
  #pragma unroll
  for (int j = 0; j < 4; ++j) {
    int i = base + t * 4 + j;
    if (i < n) out[i] = excl + run;
    run += v[j];
  }
  if (t == 255) partials[blockIdx.x] = sdata[255];
}

__global__ __launch_bounds__(256) void scan2_kernel(int* partials, int nb) {
  __shared__ int sdata[256];
  int t = threadIdx.x;
  sdata[t] = (t < nb) ? partials[t] : 0;
  __syncthreads();
  for (int off = 1; off < 256; off <<= 1) {
    int x = (t >= off) ? sdata[t - off] : 0;
    __syncthreads();
    sdata[t] += x;
    __syncthreads();
  }
  if (t < nb) partials[t] = (t == 0) ? 0 : sdata[t - 1];
}

__global__ __launch_bounds__(256) void scan3_kernel(
    int* __restrict__ out, const int* __restrict__ partials, int n, int total) {
  int i = blockIdx.x * 256 + threadIdx.x;
  if (i < n) out[i] += partials[i >> 10];
  if (i == 0) out[n] = total;
}

__global__ __launch_bounds__(256) void scatter_kernel(
    const int* __restrict__ a0i, const float* __restrict__ a0v,
    const int* __restrict__ a1i, const int* __restrict__ a2i,
    const int* __restrict__ as0, const int* __restrict__ as1,
    const int* __restrict__ G, int2* __restrict__ stag_rec,
    unsigned char* __restrict__ stag_fine) {
  __shared__ int cur[kNCB];
  int t = threadIdx.x;
  for (int i = t; i < kNCB; i += 256)
    cur[i] = G[(size_t)i * kNBA + blockIdx.x];
  __syncthreads();
  int base = blockIdx.x * kEPB;
  for (int j = 0; j < kEPB / 256; ++j) {
    int e = base + j * 256 + t;
    if (e < kTE) {
      int dst, src, boff; float val;
      edge_decode(e, a0i, a0v, a1i, a2i, as0, as1, dst, src, boff, val);
      int bin = boff + dst;
      int slot = atomicAdd(&cur[bin >> 8], 1);  // LDS atomic
      stag_rec[slot] = make_int2(src, __float_as_int(val));
      stag_fine[slot] = (unsigned char)(bin & 255);
    }
  }
}

// One block per coarse bucket (blockIdx < kNCB); remaining blocks run the
// independent gc1 GEMM tile (x @ W1 -> bf16), heterogeneous-block style (r2).
__global__ __launch_bounds__(256) void finesort_gemm_kernel(
    const int* __restrict__ G, const int2* __restrict__ stag_rec,
    const unsigned char* __restrict__ stag_fine, int* __restrict__ row_ptr,
    int2* __restrict__ edges,
    const float* __restrict__ A, const float* __restrict__ W,
    unsigned short* __restrict__ Cb, int M) {
  __shared__ float As[kGemmRows * 132];
  __shared__ int fcnt[256];
  __shared__ int fcur[256];
  int t = threadIdx.x;
  if (blockIdx.x < kNCB) {
    int b = blockIdx.x;
    int s = G[(size_t)b * kNBA];
    int e = G[(size_t)(b + 1) * kNBA];  // b=634 -> G[kGN] = kTE
    int cnt = e - s;
    fcnt[t] = 0;
    __syncthreads();
    for (int i = t; i < cnt; i += 256) atomicAdd(&fcnt[stag_fine[s + i]], 1);
    __syncthreads();
    int own = fcnt[t];
    for (int off = 1; off < 256; off <<= 1) {
      int x = (t >= off) ? fcnt[t - off] : 0;
      __syncthreads();
      fcnt[t] += x;
      __syncthreads();
    }
    int excl = fcnt[t] - own;
    int bin = (b << 8) + t;
    if (bin < kTB) row_ptr[bin] = s + excl;
    if (b == 0 && t == 0) row_ptr[kTB] = kTE;
    fcur[t] = s + excl;
    __syncthreads();
    for (int i = t; i < cnt; i += 256) {
      unsigned char f = stag_fine[s + i];
      int2 rec = stag_rec[s + i];
      int slot = atomicAdd(&fcur[f], 1);  // LDS atomic
      edges[slot] = rec;
    }
    return;
  }
  // ---- gemm path: 32-row tile of Cb = bf16(A @ W), A[M,128], W[128,128] ----
  int row0 = (blockIdx.x - kNCB) * kGemmRows;
  #pragma unroll
  for (int i = 0; i < 4; ++i) {
    int f = t + (i << 8);
    int r = f >> 5, c4 = (f & 31) << 2;
    int gr = row0 + r;
    float4 v = make_float4(0.f, 0.f, 0.f, 0.f);
    if (gr < M) v = *(const float4*)&A[(size_t)gr * 128 + c4];
    *(float4*)&As[r * 132 + c4] = v;
  }
  __syncthreads();
  int wcol = t & 31;
  int c4 = wcol << 2;
  int rsub = t >> 5;
  float4 acc[4];
  #pragma unroll
  for (int j = 0; j < 4; ++j) acc[j] = make_float4(0.f, 0.f, 0.f, 0.f);
  const float4* W4 = (const float4*)W;
  #pragma unroll 4
  for (int k = 0; k < 128; ++k) {
    float4 w = W4[k * 32 + wcol];
    #pragma unroll
    for (int j = 0; j < 4; ++j) {
      float a = As[(rsub + (j << 3)) * 132 + k];
      acc[j].x = fmaf(a, w.x, acc[j].x);
      acc[j].y = fmaf(a, w.y, acc[j].y);
      acc[j].z = fmaf(a, w.z, acc[j].z);
      acc[j].w = fmaf(a, w.w, acc[j].w);
    }
  }
  #pragma unroll
  for (int j = 0; j < 4; ++j) {
    int gr = row0 + rsub + (j << 3);
    if (gr < M) {
      ushort4 bb;
      bb.x = f2bf(acc[j].x); bb.y = f2bf(acc[j].y);
      bb.z = f2bf(acc[j].z); bb.w = f2bf(acc[j].w);
      *(ushort4*)&Cb[(size_t)gr * 128 + c4] = bb;
    }
  }
}

// Fused Q/K projection: one LDS tile of A, two K-loops (Wq -> fp32, Wk -> bf16).
__global__ __launch_bounds__(256) void gemm128_qk_kernel(
    const float* __restrict__ A, const float* __restrict__ Wq,
    const float* __restrict__ Wk, float* __restrict__ Qf,
    unsigned short* __restrict__ Kb, int M) {
  __shared__ float As[64 * 132];
  int t = threadIdx.x;
  int row0 = blockIdx.x << 6;
  #pragma unroll
  for (int i = 0; i < 8; ++i) {
    int f = t + (i << 8);
    int r = f >> 5, c4 = (f & 31) << 2;
    int gr = row0 + r;
    float4 v = make_float4(0.f, 0.f, 0.f, 0.f);
    if (gr < M) v = *(const float4*)&A[(size_t)gr * 128 + c4];
    *(float4*)&As[r * 132 + c4] = v;
  }
  __syncthreads();
  int wcol = t & 31;
  int c4 = wcol << 2;
  int rsub = t >> 5;
  float4 acc[8];
  const float4* Wq4 = (const float4*)Wq;
  const float4* Wk4 = (const float4*)Wk;
  #pragma unroll
  for (int j = 0; j < 8; ++j) acc[j] = make_float4(0.f, 0.f, 0.f, 0.f);
  #pragma unroll 4
  for (int k = 0; k < 128; ++k) {
    float4 w = Wq4[k * 32 + wcol];
    #pragma unroll
    for (int j = 0; j < 8; ++j) {
      float a = As[(rsub + (j << 3)) * 132 + k];
      acc[j].x = fmaf(a, w.x, acc[j].x);
      acc[j].y = fmaf(a, w.y, acc[j].y);
      acc[j].z = fmaf(a, w.z, acc[j].z);
      acc[j].w = fmaf(a, w.w, acc[j].w);
    }
  }
  #pragma unroll
  for (int j = 0; j < 8; ++j) {
    int gr = row0 + rsub + (j << 3);
    if (gr < M) *(float4*)&Qf[(size_t)gr * 128 + c4] = acc[j];
  }
  #pragma unroll
  for (int j = 0; j < 8; ++j) acc[j] = make_float4(0.f, 0.f, 0.f, 0.f);
  #pragma unroll 4
  for (int k = 0; k < 128; ++k) {
    float4 w = Wk4[k * 32 + wcol];
    #pragma unroll
    for (int j = 0; j < 8; ++j) {
      float a = As[(rsub + (j << 3)) * 132 + k];
      acc[j].x = fmaf(a, w.x, acc[j].x);
      acc[j].y = fmaf(a, w.y, acc[j].y);
      acc[j].z = fmaf(a, w.z, acc[j].z);
      acc[j].w = fmaf(a, w.w, acc[j].w);
    }
  }
  #pragma unroll
  for (int j = 0; j < 8; ++j) {
    int gr = row0 + rsub + (j << 3);
    if (gr < M) {
      ushort4 b;
      b.x = f2bf(acc[j].x); b.y = f2bf(acc[j].y);
      b.z = f2bf(acc[j].z); b.w = f2bf(acc[j].w);
      *(ushort4*)&Kb[(size_t)gr * 128 + c4] = b;
    }
  }
}

// C[M,40] = A[M,128] @ W[128,40], bf16 output (consumed by gathers only)
__global__ __launch_bounds__(256) void gemm40_kernel(
    const float* __restrict__ A, const float* __restrict__ W,
    unsigned short* __restrict__ Cb, int M) {
  __shared__ float Ws[128 * 40];
  __shared__ float As[64 * 132];
  int t = threadIdx.x;
  int row0 = blockIdx.x << 6;
  #pragma unroll
  for (int i = 0; i < 5; ++i)
    ((float4*)Ws)[t + i * 256] = ((const float4*)W)[t + i * 256];
  #pragma unroll
  for (int i = 0; i < 8; ++i) {
    int f = t + (i << 8);
    int r = f >> 5, c4 = (f & 31) << 2;
    int gr = row0 + r;
    float4 v = make_float4(0.f, 0.f, 0.f, 0.f);
    if (gr < M) v = *(const float4*)&A[(size_t)gr * 128 + c4];
    *(float4*)&As[r * 132 + c4] = v;
  }
  __syncthreads();
  int r = t >> 2;
  int cg = (t & 3) * 10;
  float acc[10];
  #pragma unroll
  for (int j = 0; j < 10; ++j) acc[j] = 0.f;
  for (int k = 0; k < 128; ++k) {
    float a = As[r * 132 + k];
    #pragma unroll
    for (int j = 0; j < 10; ++j) acc[j] = fmaf(a, Ws[k * 40 + cg + j], acc[j]);
  }
  int gr = row0 + r;
  if (gr < M) {
    #pragma unroll
    for (int j = 0; j < 10; ++j) Cb[(size_t)gr * 40 + cg + j] = f2bf(acc[j]);
  }
}

// ---------------------------------------------------------------------------
// Pull-SpMM over CSR: one wave per dst row, 128 cols (2/lane), 4-way MLP.
// ---------------------------------------------------------------------------
template <bool BF16>
__global__ __launch_bounds__(256) void spmm128_kernel(
    const int* __restrict__ row_ptr, const int2* __restrict__ edges,
    const void* __restrict__ Xv, float* __restrict__ Y,
    const float* __restrict__ bias, int nrows, int do_relu) {
  int wid = (blockIdx.x * 256 + threadIdx.x) >> 6;
  int lane = threadIdx.x & 63;
  if (wid >= nrows) return;
  int start = row_ptr[wid], end = row_ptr[wid + 1];
  const unsigned short* Xb = (const unsigned short*)Xv;
  const float* Xf = (const float*)Xv;
  float2 accA = make_float2(0.f, 0.f), accB = make_float2(0.f, 0.f);
  for (int base = start; base < end; base += 64) {
    int cnt = end - base; if (cnt > 64) cnt = 64;
    int2 e_l = make_int2(0, 0);
    if (lane < cnt) e_l = edges[base + lane];
    int j = 0;
    for (; j + 4 <= cnt; j += 4) {
      int s0 = __shfl(e_l.x, j + 0), s1 = __shfl(e_l.x, j + 1);
      int s2 = __shfl(e_l.x, j + 2), s3 = __shfl(e_l.x, j + 3);
      float v0 = __int_as_float(__shfl(e_l.y, j + 0));
      float v1 = __int_as_float(__shfl(e_l.y, j + 1));
      float v2 = __int_as_float(__shfl(e_l.y, j + 2));
      float v3 = __int_as_float(__shfl(e_l.y, j + 3));
      if (BF16) {
        unsigned int u0 = *(const unsigned int*)(Xb + (size_t)s0 * 128 + lane * 2);
        unsigned int u1 = *(const unsigned int*)(Xb + (size_t)s1 * 128 + lane * 2);
        unsigned int u2 = *(const unsigned int*)(Xb + (size_t)s2 * 128 + lane * 2);
        unsigned int u3 = *(const unsigned int*)(Xb + (size_t)s3 * 128 + lane * 2);
        accA.x = fmaf(v0, bf_lo(u0), accA.x); accA.y = fmaf(v0, bf_hi(u0), accA.y);
        accB.x = fmaf(v1, bf_lo(u1), accB.x); accB.y = fmaf(v1, bf_hi(u1), accB.y);
        accA.x = fmaf(v2, bf_lo(u2), accA.x); accA.y = fmaf(v2, bf_hi(u2), accA.y);
        accB.x = fmaf(v3, bf_lo(u3), accB.x); accB.y = fmaf(v3, bf_hi(u3), accB.y);
      } else {
        float2 x0 = *(const float2*)(Xf + (size_t)s0 * 128 + lane * 2);
        float2 x1 = *(const float2*)(Xf + (size_t)s1 * 128 + lane * 2);
        float2 x2 = *(const float2*)(Xf + (size_t)s2 * 128 + lane * 2);
        float2 x3 = *(const float2*)(Xf + (size_t)s3 * 128 + lane * 2);
        accA.x = fmaf(v0, x0.x, accA.x); accA.y = fmaf(v0, x0.y, accA.y);
        accB.x = fmaf(v1, x1.x, accB.x); accB.y = fmaf(v1, x1.y, accB.y);
        accA.x = fmaf(v2, x2.x, accA.x); accA.y = fmaf(v2, x2.y, accA.y);
        accB.x = fmaf(v3, x3.x, accB.x); accB.y = fmaf(v3, x3.y, accB.y);
      }
    }
    for (; j < cnt; ++j) {
      int src = __shfl(e_l.x, j);
      float val = __int_as_float(__shfl(e_l.y, j));
      if (BF16) {
        unsigned int u = *(const unsigned int*)(Xb + (size_t)src * 128 + lane * 2);
        accA.x = fmaf(val, bf_lo(u), accA.x);
        accA.y = fmaf(val, bf_hi(u), accA.y);
      } else {
        float2 xv = *(const float2*)(Xf + (size_t)src * 128 + lane * 2);
        accA.x = fmaf(val, xv.x, accA.x);
        accA.y = fmaf(val, xv.y, accA.y);
      }
    }
  }
  float2 acc = make_float2(accA.x + accB.x, accA.y + accB.y);
  if (bias) { acc.x += bias[lane * 2]; acc.y += bias[lane * 2 + 1]; }
  if (do_relu) { acc.x = fmaxf(acc.x, 0.f); acc.y = fmaxf(acc.y, 0.f); }
  *(float2*)&Y[(size_t)wid * 128 + lane * 2] = acc;
}

// Pool (T-graph pull sum) fused with nwgt-embedding add, 4-way MLP.
__global__ __launch_bounds__(256) void pool_emb_kernel(
    const int* __restrict__ row_ptr, const int2* __restrict__ edges,
    const float* __restrict__ X, const int* __restrict__ nwgt,
    const float* __restrict__ emb, float* __restrict__ Hpool,
    float* __restrict__ H0, unsigned short* __restrict__ H0b, int nrows) {
  int wid = (blockIdx.x * 256 + threadIdx.x) >> 6;
  int lane = threadIdx.x & 63;
  if (wid >= nrows) return;
  int start = row_ptr[wid], end = row_ptr[wid + 1];
  float2 accA = make_float2(0.f, 0.f), accB = make_float2(0.f, 0.f);
  for (int base = start; base < end; base += 64) {
    int cnt = end - base; if (cnt > 64) cnt = 64;
    int s_l = 0;
    if (lane < cnt) s_l = edges[base + lane].x;
    int j = 0;
    for (; j + 4 <= cnt; j += 4) {
      int s0 = __shfl(s_l, j + 0), s1 = __shfl(s_l, j + 1);
      int s2 = __shfl(s_l, j + 2), s3 = __shfl(s_l, j + 3);
      float2 x0 = *(const float2*)&X[(size_t)s0 * 128 + lane * 2];
      float2 x1 = *(const float2*)&X[(size_t)s1 * 128 + lane * 2];
      float2 x2 = *(const float2*)&X[(size_t)s2 * 128 + lane * 2];
      float2 x3 = *(const float2*)&X[(size_t)s3 * 128 + lane * 2];
      accA.x += x0.x + x2.x; accA.y += x0.y + x2.y;
      accB.x += x1.x + x3.x; accB.y += x1.y + x3.y;
    }
    for (; j < cnt; ++j) {
      int src = __shfl(s_l, j);
      float2 xv = *(const float2*)&X[(size_t)src * 128 + lane * 2];
      accA.x += xv.x; accA.y += xv.y;
    }
  }
  float2 acc = make_float2(accA.x + accB.x, accA.y + accB.y);
  *(float2*)&Hpool[(size_t)wid * 128 + lane * 2] = acc;
  float2 ev = *(const float2*)&emb[(size_t)nwgt[wid] * 128 + lane * 2];
  float2 h0 = make_float2(acc.x + ev.x, acc.y + ev.y);
  *(float2*)&H0[(size_t)wid * 128 + lane * 2] = h0;
  unsigned int packed = ((unsigned int)f2bf(h0.x)) | (((unsigned int)f2bf(h0.y)) << 16);
  *(unsigned int*)(H0b + (size_t)wid * 128 + lane * 2) = packed;
}

__global__ __launch_bounds__(256) void spmm40_kernel(
    const int* __restrict__ row_ptr, const int2* __restrict__ edges,
    const unsigned short* __restrict__ Xb, float* __restrict__ Y,
    const float* __restrict__ bias, int nrows) {
  int wid = (blockIdx.x * 256 + threadIdx.x) >> 6;
  int lane = threadIdx.x & 63;
  if (wid >= nrows) return;
  int start = row_ptr[wid], end = row_ptr[wid + 1];
  float accA = 0.f, accB = 0.f;
  for (int base = start; base < end; base += 64) {
    int cnt = end - base; if (cnt > 64) cnt = 64;
    int2 e_l = make_int2(0, 0);
    if (lane < cnt) e_l = edges[base + lane];
    int j = 0;
    for (; j + 4 <= cnt; j += 4) {
      int s0 = __shfl(e_l.x, j + 0), s1 = __shfl(e_l.x, j + 1);
      int s2 = __shfl(e_l.x, j + 2), s3 = __shfl(e_l.x, j + 3);
      float v0 = __int_as_float(__shfl(e_l.y, j + 0));
      float v1 = __int_as_float(__shfl(e_l.y, j + 1));
      float v2 = __int_as_float(__shfl(e_l.y, j + 2));
      float v3 = __int_as_float(__shfl(e_l.y, j + 3));
      if (lane < 40) {
        unsigned short u0 = Xb[(size_t)s0 * 40 + lane];
        unsigned short u1 = Xb[(size_t)s1 * 40 + lane];
        unsigned short u2 = Xb[(size_t)s2 * 40 + lane];
        unsigned short u3 = Xb[(size_t)s3 * 40 + lane];
        accA = fmaf(v0, __uint_as_float(((unsigned int)u0) << 16), accA);
        accB = fmaf(v1, __uint_as_float(((unsigned int)u1) << 16), accB);
        accA = fmaf(v2, __uint_as_float(((unsigned int)u2) << 16), accA);
        accB = fmaf(v3, __uint_as_float(((unsigned int)u3) << 16), accB);
      }
    }
    for (; j < cnt; ++j) {
      int src = __shfl(e_l.x, j);
      float val = __int_as_float(__shfl(e_l.y, j));
      if (lane < 40) {
        unsigned short u = Xb[(size_t)src * 40 + lane];
        accA = fmaf(val, __uint_as_float(((unsigned int)u) << 16), accA);
      }
    }
  }
  if (lane < 40) Y[(size_t)wid * 40 + lane] = accA + accB + bias[lane];
}

// ---------------------------------------------------------------------------
// Fused CRF row kernel, 4 edges per step: batched k/h0 gathers (8 loads in
// flight), 4 interleaved butterfly dot-reductions, one online-softmax update.
// ---------------------------------------------------------------------------
__global__ __launch_bounds__(256) void crf_fused_kernel(
    const int* __restrict__ row_ptr, const int2* __restrict__ edges,
    const float* __restrict__ Q, const unsigned short* __restrict__ Kb,
    const float* __restrict__ H0, const unsigned short* __restrict__ H0b,
    float* __restrict__ Y, const float* __restrict__ alpha_p,
    const float* __restrict__ beta_p, int nrows) {
  int wid = (blockIdx.x * 256 + threadIdx.x) >> 6;
  int lane = threadIdx.x & 63;
  if (wid >= nrows) return;
  int start = row_ptr[wid], end = row_ptr[wid + 1];
  float2 qv = *(const float2*)&Q[(size_t)wid * 128 + lane * 2];
  const float kScale = 0.08838834764831845f;  // 1/sqrt(128)
  float m = -3.4e38f, z = 0.f;
  float2 msg = make_float2(0.f, 0.f);
  for (int base = start; base < end; base += 64) {
    int cnt = end - base; if (cnt > 64) cnt = 64;
    int s_l = 0;
    if (lane < cnt) s_l = edges[base + lane].x;
    int j = 0;
    for (; j + 4 <= cnt; j += 4) {
      int s0 = __shfl(s_l, j + 0), s1 = __shfl(s_l, j + 1);
      int s2 = __shfl(s_l, j + 2), s3 = __shfl(s_l, j + 3);
      unsigned int k0 = *(const unsigned int*)(Kb + (size_t)s0 * 128 + lane * 2);
      unsigned int k1 = *(const unsigned int*)(Kb + (size_t)s1 * 128 + lane * 2);
      unsigned int k2 = *(const unsigned int*)(Kb + (size_t)s2 * 128 + lane * 2);
      unsigned int k3 = *(const unsigned int*)(Kb + (size_t)s3 * 128 + lane * 2);
      unsigned int h0 = *(const unsigned int*)(H0b + (size_t)s0 * 128 + lane * 2);
      unsigned int h1 = *(const unsigned int*)(H0b + (size_t)s1 * 128 + lane * 2);
      unsigned int h2 = *(const unsigned int*)(H0b + (size_t)s2 * 128 + lane * 2);
      unsigned int h3 = *(const unsigned int*)(H0b + (size_t)s3 * 128 + lane * 2);
      float p0 = qv.x * bf_lo(k0) + qv.y * bf_hi(k0);
      float p1 = qv.x * bf_lo(k1) + qv.y * bf_hi(k1);
      float p2 = qv.x * bf_lo(k2) + qv.y * bf_hi(k2);
      float p3 = qv.x * bf_lo(k3) + qv.y * bf_hi(k3);
      #pragma unroll
      for (int d = 32; d >= 1; d >>= 1) {
        p0 += __shfl_xor(p0, d);
        p1 += __shfl_xor(p1, d);
        p2 += __shfl_xor(p2, d);
        p3 += __shfl_xor(p3, d);
      }
      p0 *= kScale; p1 *= kScale; p2 *= kScale; p3 *= kScale;
      float pm = fmaxf(fmaxf(p0, p1), fmaxf(p2, p3));
      float mn = fmaxf(m, pm);
      float corr = __expf(m - mn);
      float w0 = __expf(p0 - mn), w1 = __expf(p1 - mn);
      float w2 = __expf(p2 - mn), w3 = __expf(p3 - mn);
      z = z * corr + (w0 + w1) + (w2 + w3);
      msg.x = msg.x * corr + w0 * bf_lo(h0) + w1 * bf_lo(h1)
                           + w2 * bf_lo(h2) + w3 * bf_lo(h3);
      msg.y = msg.y * corr + w0 * bf_hi(h0) + w1 * bf_hi(h1)
                           + w2 * bf_hi(h2) + w3 * bf_hi(h3);
      m = mn;
    }
    for (; j < cnt; ++j) {
      int src = __shfl(s_l, j);
      unsigned int ku = *(const unsigned int*)(Kb + (size_t)src * 128 + lane * 2);
      unsigned int hu = *(const unsigned int*)(H0b + (size_t)src * 128 + lane * 2);
      float p = qv.x * bf_lo(ku) + qv.y * bf_hi(ku);
      #pragma unroll
      for (int d = 32; d >= 1; d >>= 1) p += __shfl_xor(p, d);
      p *= kScale;
      float mn = fmaxf(m, p);
      float corr = __expf(m - mn);
      float w = __expf(p - mn);
      z = z * corr + w;
      msg.x = msg.x * corr + w * bf_lo(hu);
      msg.y = msg.y * corr + w * bf_hi(hu);
      m = mn;
    }
  }
  float alpha = *alpha_p, beta = *beta_p;
  float inv = 1.0f / (z + 1e-16f);
  float2 h0i = *(const float2*)&H0[(size_t)wid * 128 + lane * 2];
  float sc = 1.0f / (alpha + beta);
  float2 o;
  o.x = (alpha * h0i.x + beta * (msg.x * inv)) * sc;
  o.y = (alpha * h0i.y + beta * (msg.y * inv)) * sc;
  *(float2*)&Y[(size_t)wid * 128 + lane * 2] = o;
}

// Fused double unpool: crf_h[r] = h2[assign1[assign0[r]]] + h1[assign0[r]] + gcn[r]
__global__ __launch_bounds__(256) void unpool2_kernel(
    const float* __restrict__ H2, const float* __restrict__ H1,
    const float* __restrict__ Gcn, const int* __restrict__ assign0,
    const int* __restrict__ assign1, float* __restrict__ Y, int nrows) {
  int wid = (blockIdx.x * 256 + threadIdx.x) >> 6;
  int lane = threadIdx.x & 63;
  if (wid >= nrows) return;
  int a0 = assign0[wid];
  int a1 = assign1[a0];
  float2 v2 = *(const float2*)&H2[(size_t)a1 * 128 + lane * 2];
  float2 v1 = *(const float2*)&H1[(size_t)a0 * 128 + lane * 2];
  float2 vg = *(const float2*)&Gcn[(size_t)wid * 128 + lane * 2];
  float2 o = make_float2(v2.x + v1.x + vg.x, v2.y + v1.y + vg.y);
  *(float2*)&Y[(size_t)wid * 128 + lane * 2] = o;
}

}  // namespace

// ---------------------------------------------------------------------------
extern "C" void kernel_launch(void* const* d_in, const int* in_sizes, int n_in,
                              void* d_out, int out_size, void* d_ws, size_t ws_size,
                              hipStream_t stream) {
  const float* x       = (const float*)d_in[0];
  const int*   A0_idx  = (const int*)d_in[1];
  const float* A0_val  = (const float*)d_in[2];
  const int*   A1_idx  = (const int*)d_in[3];
  const int*   A2_idx  = (const int*)d_in[5];
  const int*   assign0 = (const int*)d_in[7];
  const int*   assign1 = (const int*)d_in[8];
  const int*   nwgt1   = (const int*)d_in[9];
  const int*   nwgt2   = (const int*)d_in[10];
  const float* gc1_W   = (const float*)d_in[11];
  const float* gc1_b   = (const float*)d_in[12];
  const float* gc2_W   = (const float*)d_in[13];
  const float* gc2_b   = (const float*)d_in[14];
  const float* c1_Wq   = (const float*)d_in[15];
  const float* c1_Wk   = (const float*)d_in[16];
  const float* c1_emb  = (const float*)d_in[17];
  const float* c1_al   = (const float*)d_in[18];
  const float* c1_be   = (const float*)d_in[19];
  const float* c2_Wq   = (const float*)d_in[20];
  const float* c2_Wk   = (const float*)d_in[21];
  const float* c2_emb  = (const float*)d_in[22];
  const float* c2_al   = (const float*)d_in[23];
  const float* c2_be   = (const float*)d_in[24];

  float* out_g = (float*)d_out;                      // [N0, 40]
  float* gcn_h = out_g + (size_t)kN0 * 40;           // [N0, 128]
  float* crf_h = gcn_h + (size_t)kN0 * 128;          // [N0, 128]

  // ---- workspace carving ----
  char* ws = (char*)d_ws;
  size_t off = 0;
  auto carve = [&](size_t bytes) -> void* {
    void* p = ws + off;
    off += (bytes + 511) & ~(size_t)511;
    return p;
  };
  int*   G        = (int*)carve((size_t)(kGN + 1) * 4);    // 691 KB bucket matrix
  int*   row_ptr  = (int*)carve((size_t)(kTB + 1) * 4);
  int*   partials = (int*)carve(1024);
  int2*  edges    = (int2*)carve((size_t)kTE * 8);         // 17.8 MB
  float* h1_crf   = (float*)carve((size_t)kN1 * 128 * 4);  // 12.8 MB, long-lived
  char*  arena    = (char*)carve(51200000 + 4096);         // reused overlays
  // Overlays (byte offsets; lifetimes vs launch order):
  unsigned short* xWb   = (unsigned short*)(arena);              // [finesort-gemm .. gc1 spmm]
  int2* stag_rec = (int2*)(arena + 25600000);                    // [scatter .. finesort]
  unsigned char* stag_fine = (unsigned char*)(arena + 43400000); // [scatter .. finesort]
  float* h1_pool = (float*)(arena);                              // [pool1 .. qk1]
  float* h0_1    = (float*)(arena + 12800000);                   // [pool1 .. crf1]
  unsigned short* h0_1b = (unsigned short*)(arena + 25600000);   // [pool1 .. crf1]
  float* q1      = (float*)(arena + 32000000);                   // [qk1 .. crf1]
  unsigned short* k1b   = (unsigned short*)(arena + 44800000);   // [qk1 .. crf1]
  float* h2_pool = (float*)(arena);                              // [pool2 .. qk2]
  float* h0_2    = (float*)(arena + 3200000);                    // [pool2 .. crf2]
  unsigned short* h0_2b = (unsigned short*)(arena + 6400000);    // [pool2 .. crf2]
  float* q2      = (float*)(arena + 8000000);                    // [qk2 .. crf2]
  unsigned short* k2b   = (unsigned short*)(arena + 11200000);   // [qk2 .. crf2]
  float* h2_crf  = (float*)(arena + 12800000);                   // [crf2 .. unpool]
  unsigned short* hW2b  = (unsigned short*)(arena);              // [gemm40 .. spmm40]
  // stag_* are dead before pool1 writes h1_pool/h0_1b; xWb [0,25.6M) is
  // disjoint from stag_* [25.6M,45.63M) during the finesort+gemm dispatch.

  // ---- 1. CSR build: hist -> scan(G) -> scatter -> finesort (+gc1 gemm) ----
  hist_kernel<<<kNBA, 256, 0, stream>>>(A0_idx, A1_idx, A2_idx,
                                        assign0, assign1, G);
  scan1_kernel<<<kNBLK_G, 256, 0, stream>>>(G, G, partials, kGN);
  scan2_kernel<<<1, 256, 0, stream>>>(partials, kNBLK_G);
  scan3_kernel<<<(kGN + 255) / 256, 256, 0, stream>>>(G, partials, kGN, kTE);
  scatter_kernel<<<kNBA, 256, 0, stream>>>(A0_idx, A0_val, A1_idx, A2_idx,
                                           assign0, assign1, G, stag_rec,
                                           stag_fine);
  finesort_gemm_kernel<<<kNCB + kGemmBlocks, 256, 0, stream>>>(
      G, stag_rec, stag_fine, row_ptr, edges, x, gc1_W, xWb, kN0);

  // ---- 2. gc1 aggregation: h = relu(A0 @ (x W1) + b1) -> gcn_hidden ----
  spmm128_kernel<true><<<(kN0 + 3) / 4, 256, 0, stream>>>(row_ptr, edges, xWb,
                                                          gcn_h, gc1_b, kN0, 1);
  // ---- 3. level-1 pool(+emb) + QK + CRF ----
  pool_emb_kernel<<<(kN1 + 3) / 4, 256, 0, stream>>>(row_ptr + kBO3, edges, gcn_h,
                                                     nwgt1, c1_emb, h1_pool, h0_1,
                                                     h0_1b, kN1);
  gemm128_qk_kernel<<<(kN1 + 63) / 64, 256, 0, stream>>>(h1_pool, c1_Wq, c1_Wk,
                                                         q1, k1b, kN1);
  crf_fused_kernel<<<(kN1 + 3) / 4, 256, 0, stream>>>(row_ptr + kBO1, edges, q1, k1b,
                                                      h0_1, h0_1b, h1_crf, c1_al,
                                                      c1_be, kN1);
  // ---- 4. level-2 pool(+emb) + QK + CRF ----
  pool_emb_kernel<<<(kN2 + 3) / 4, 256, 0, stream>>>(row_ptr + kBO4, edges, h1_crf,
                                                     nwgt2, c2_emb, h2_pool, h0_2,
                                                     h0_2b, kN2);
  gemm128_qk_kernel<<<(kN2 + 63) / 64, 256, 0, stream>>>(h2_pool, c2_Wq, c2_Wk,
                                                         q2, k2b, kN2);
  crf_fused_kernel<<<(kN2 + 3) / 4, 256, 0, stream>>>(row_ptr + kBO2, edges, q2, k2b,
                                                      h0_2, h0_2b, h2_crf, c2_al,
                                                      c2_be, kN2);
  // ---- 5. fused double unpool with skips -> crf_hidden ----
  unpool2_kernel<<<(kN0 + 3) / 4, 256, 0, stream>>>(h2_crf, h1_crf, gcn_h,
                                                    assign0, assign1, crf_h, kN0);
  // ---- 6. gc2: out = A0 @ (crf_hidden W2) + b2 ----
  gemm40_kernel<<<(kN0 + 63) / 64, 256, 0, stream>>>(crf_h, gc2_W, hW2b, kN0);
  spmm40_kernel<<<(kN0 + 3) / 4, 256, 0, stream>>>(row_ptr, edges, hW2b,
                                                   out_g, gc2_b, kN0);
}